// Round 1
// baseline (1973.617 us; speedup 1.0000x reference)
//
#include <hip/hip_runtime.h>

#define N_NODES 100000
#define N_EDGES 1600000
#define FIN 512
#define FHID 128
#define FOUT 40

// ---------------- degree + norms ----------------
__global__ void deg_kernel(const int* __restrict__ src, const int* __restrict__ dst,
                           unsigned* __restrict__ deg_out, unsigned* __restrict__ deg_in) {
    int e = blockIdx.x * blockDim.x + threadIdx.x;
    if (e < N_EDGES) {
        atomicAdd(&deg_out[src[e]], 1u);
        atomicAdd(&deg_in[dst[e]], 1u);
    }
}

__global__ void norm_kernel(const unsigned* __restrict__ deg_out, const unsigned* __restrict__ deg_in,
                            float* __restrict__ nsrc, float* __restrict__ ndst) {
    int i = blockIdx.x * blockDim.x + threadIdx.x;
    if (i < N_NODES) {
        unsigned o = deg_out[i]; if (o < 1u) o = 1u;
        unsigned d = deg_in[i];  if (d < 1u) d = 1u;
        nsrc[i] = rsqrtf((float)o);
        ndst[i] = rsqrtf((float)d);
    }
}

// ---------------- GEMM1: H = (X * nsrc) @ W1   [100000x512]@[512x128] ----------------
#define BM 64
#define BK 32
__global__ __launch_bounds__(256) void gemm1_kernel(const float* __restrict__ X,
                                                    const float* __restrict__ W,
                                                    const float* __restrict__ nsrc,
                                                    float* __restrict__ H) {
    __shared__ float Xs[BM][BK + 1];
    __shared__ float Ws[BK][FHID];
    const int bm = blockIdx.x * BM;
    const int t = threadIdx.x;
    const int ty = t >> 4;   // 0..15 -> 4-row group
    const int tx = t & 15;   // 0..15 -> 8-col group

    float acc[4][8];
#pragma unroll
    for (int i = 0; i < 4; i++)
#pragma unroll
        for (int j = 0; j < 8; j++) acc[i][j] = 0.f;

    for (int k0 = 0; k0 < FIN; k0 += BK) {
        // stage X tile (64 x 32), scaled by nsrc: 512 float4, 2 per thread
#pragma unroll
        for (int l = 0; l < 2; l++) {
            int idx = t + l * 256;      // 0..511
            int r = idx >> 3;           // 0..63
            int c4 = idx & 7;           // 0..7
            int row = bm + r;
            float4 v = make_float4(0.f, 0.f, 0.f, 0.f);
            if (row < N_NODES) {
                v = *(const float4*)(X + (size_t)row * FIN + k0 + c4 * 4);
                float s = nsrc[row];
                v.x *= s; v.y *= s; v.z *= s; v.w *= s;
            }
            Xs[r][c4 * 4 + 0] = v.x; Xs[r][c4 * 4 + 1] = v.y;
            Xs[r][c4 * 4 + 2] = v.z; Xs[r][c4 * 4 + 3] = v.w;
        }
        // stage W tile (32 x 128): 1024 float4, 4 per thread
#pragma unroll
        for (int l = 0; l < 4; l++) {
            int idx = t + l * 256;      // 0..1023
            int r = idx >> 5;           // 0..31
            int c4 = idx & 31;          // 0..31
            float4 v = *(const float4*)(W + (size_t)(k0 + r) * FHID + c4 * 4);
            *(float4*)&Ws[r][c4 * 4] = v;
        }
        __syncthreads();
#pragma unroll
        for (int kk = 0; kk < BK; kk++) {
            float a[4], b[8];
#pragma unroll
            for (int i = 0; i < 4; i++) a[i] = Xs[ty * 4 + i][kk];
#pragma unroll
            for (int j = 0; j < 8; j++) b[j] = Ws[kk][tx * 8 + j];
#pragma unroll
            for (int i = 0; i < 4; i++)
#pragma unroll
                for (int j = 0; j < 8; j++)
                    acc[i][j] = fmaf(a[i], b[j], acc[i][j]);
        }
        __syncthreads();
    }
#pragma unroll
    for (int i = 0; i < 4; i++) {
        int row = bm + ty * 4 + i;
        if (row < N_NODES) {
#pragma unroll
            for (int j = 0; j < 8; j += 4) {
                float4 v = make_float4(acc[i][j], acc[i][j + 1], acc[i][j + 2], acc[i][j + 3]);
                *(float4*)(H + (size_t)row * FHID + tx * 8 + j) = v;
            }
        }
    }
}

// ---------------- SpMM1: AGG[dst] += H[src]  (128 feats, atomic scatter) ----------------
__global__ void spmm1_kernel(const int* __restrict__ src, const int* __restrict__ dst,
                             const float* __restrict__ H, float* __restrict__ AGG) {
    int gtid = blockIdx.x * blockDim.x + threadIdx.x;
    int wave = gtid >> 6;
    int lane = threadIdx.x & 63;
    int nwaves = (gridDim.x * blockDim.x) >> 6;
    for (int e = wave; e < N_EDGES; e += nwaves) {
        int s = src[e];
        int d = dst[e];
        float2 v = *(const float2*)(H + (size_t)s * FHID + lane * 2);
        float* a = AGG + (size_t)d * FHID + lane * 2;
        atomicAdd(a + 0, v.x);
        atomicAdd(a + 1, v.y);
    }
}

// ---------------- finish1: X2 = relu(AGG * ndst + b1) ----------------
__global__ void finish1_kernel(const float* __restrict__ AGG, const float* __restrict__ ndst,
                               const float* __restrict__ b1, float* __restrict__ X2) {
    int stride = gridDim.x * blockDim.x;
    const int total = N_NODES * FHID / 4;   // 3.2M float4
    for (int i = blockIdx.x * blockDim.x + threadIdx.x; i < total; i += stride) {
        int row = i >> 5;
        int c4 = (i & 31) << 2;
        float s = ndst[row];
        float4 v = ((const float4*)AGG)[i];
        float4 b = *(const float4*)(b1 + c4);
        v.x = fmaxf(fmaf(v.x, s, b.x), 0.f);
        v.y = fmaxf(fmaf(v.y, s, b.y), 0.f);
        v.z = fmaxf(fmaf(v.z, s, b.z), 0.f);
        v.w = fmaxf(fmaf(v.w, s, b.w), 0.f);
        ((float4*)X2)[i] = v;
    }
}

// ---------------- GEMM2: H2 = (X2 * nsrc) @ W2   [100000x128]@[128x40] ----------------
__global__ __launch_bounds__(320) void gemm2_kernel(const float* __restrict__ X2,
                                                    const float* __restrict__ W2,
                                                    const float* __restrict__ nsrc,
                                                    float* __restrict__ H2) {
    __shared__ float Ws[FHID][FOUT];  // 20.5KB
    __shared__ float Xs[32][FHID];    // 16KB
    const int t = threadIdx.x;
    const int bm = blockIdx.x * 32;
    for (int idx = t; idx < FHID * FOUT; idx += 320)
        Ws[idx / FOUT][idx % FOUT] = W2[idx];
    for (int idx = t; idx < 32 * FHID / 4; idx += 320) {
        int r = idx >> 5;          // 0..31
        int c4 = idx & 31;         // 0..31
        int row = bm + r;
        float4 v = make_float4(0.f, 0.f, 0.f, 0.f);
        if (row < N_NODES) {
            v = *(const float4*)(X2 + (size_t)row * FHID + c4 * 4);
            float s = nsrc[row];
            v.x *= s; v.y *= s; v.z *= s; v.w *= s;
        }
        *(float4*)&Xs[r][c4 * 4] = v;
    }
    __syncthreads();
    const int r0 = t / FOUT;   // 0..7
    const int c = t % FOUT;
    float acc[4] = {0.f, 0.f, 0.f, 0.f};
    for (int k = 0; k < FHID; k++) {
        float b = Ws[k][c];
#pragma unroll
        for (int i = 0; i < 4; i++)
            acc[i] = fmaf(Xs[r0 + i * 8][k], b, acc[i]);
    }
#pragma unroll
    for (int i = 0; i < 4; i++) {
        int row = bm + r0 + i * 8;
        if (row < N_NODES) H2[(size_t)row * FOUT + c] = acc[i];
    }
}

// ---------------- SpMM2: OUT[dst] += H2[src]  (40 feats, atomic scatter) ----------------
__global__ void spmm2_kernel(const int* __restrict__ src, const int* __restrict__ dst,
                             const float* __restrict__ H2, float* __restrict__ OUT) {
    int gtid = blockIdx.x * blockDim.x + threadIdx.x;
    int wave = gtid >> 6;
    int lane = threadIdx.x & 63;
    int nwaves = (gridDim.x * blockDim.x) >> 6;
    for (int e = wave; e < N_EDGES; e += nwaves) {
        int s = src[e];
        int d = dst[e];
        if (lane < FOUT) {
            float v = H2[(size_t)s * FOUT + lane];
            atomicAdd(&OUT[(size_t)d * FOUT + lane], v);
        }
    }
}

// ---------------- finish2: OUT = OUT * ndst + b2 (in place) ----------------
__global__ void finish2_kernel(float* __restrict__ OUT, const float* __restrict__ ndst,
                               const float* __restrict__ b2) {
    int stride = gridDim.x * blockDim.x;
    const int total = N_NODES * FOUT / 4;   // 1M float4
    for (int i = blockIdx.x * blockDim.x + threadIdx.x; i < total; i += stride) {
        int row = i / 10;
        int c4 = (i % 10) << 2;
        float s = ndst[row];
        float4 v = ((float4*)OUT)[i];
        float4 b = *(const float4*)(b2 + c4);
        v.x = fmaf(v.x, s, b.x);
        v.y = fmaf(v.y, s, b.y);
        v.z = fmaf(v.z, s, b.z);
        v.w = fmaf(v.w, s, b.w);
        ((float4*)OUT)[i] = v;
    }
}

extern "C" void kernel_launch(void* const* d_in, const int* in_sizes, int n_in,
                              void* d_out, int out_size, void* d_ws, size_t ws_size,
                              hipStream_t stream) {
    const float* feat = (const float*)d_in[0];
    const int*   src  = (const int*)d_in[1];
    const int*   dst  = (const int*)d_in[2];
    const float* W1   = (const float*)d_in[3];
    const float* b1   = (const float*)d_in[4];
    const float* W2   = (const float*)d_in[5];
    const float* b2   = (const float*)d_in[6];
    float* out = (float*)d_out;

    char* ws = (char*)d_ws;
    const size_t SZ_BIG = (size_t)N_NODES * FHID * sizeof(float);   // 51.2 MB
    float* bufA = (float*)ws;                    // h1, then x2
    float* bufB = (float*)(ws + SZ_BIG);         // agg1, then h2
    char*  small = ws + 2 * SZ_BIG;
    const size_t SSTRIDE = 401408;               // 512-aligned, >= 400000 B
    unsigned* degO = (unsigned*)(small);
    unsigned* degI = (unsigned*)(small + SSTRIDE);
    float* nsrc = (float*)(small + 2 * SSTRIDE);
    float* ndst = (float*)(small + 3 * SSTRIDE);

    // zero accumulation targets (harness does not re-zero between replays)
    hipMemsetAsync(small, 0, 2 * SSTRIDE, stream);
    hipMemsetAsync(bufB, 0, SZ_BIG, stream);
    hipMemsetAsync(d_out, 0, (size_t)out_size * sizeof(float), stream);

    deg_kernel<<<(N_EDGES + 255) / 256, 256, 0, stream>>>(src, dst, degO, degI);
    norm_kernel<<<(N_NODES + 255) / 256, 256, 0, stream>>>(degO, degI, nsrc, ndst);
    gemm1_kernel<<<(N_NODES + BM - 1) / BM, 256, 0, stream>>>(feat, W1, nsrc, bufA);
    spmm1_kernel<<<2048, 256, 0, stream>>>(src, dst, bufA, bufB);
    finish1_kernel<<<2048, 256, 0, stream>>>(bufB, ndst, b1, bufA);
    gemm2_kernel<<<(N_NODES + 31) / 32, 320, 0, stream>>>(bufA, W2, nsrc, bufB);
    spmm2_kernel<<<2048, 256, 0, stream>>>(src, dst, bufB, out);
    finish2_kernel<<<1024, 256, 0, stream>>>(out, ndst, b2);
}

// Round 2
// 703.549 us; speedup vs baseline: 2.8052x; 2.8052x over previous
//
#include <hip/hip_runtime.h>

#define N_NODES 100000
#define N_EDGES 1600000
#define FIN 512
#define FHID 128
#define FOUT 40

#define SCAN_CHUNK 1024
#define SCAN_NB ((N_NODES + SCAN_CHUNK - 1) / SCAN_CHUNK)   // 98

// ---------------- degree ----------------
__global__ void deg_kernel(const int* __restrict__ src, const int* __restrict__ dst,
                           unsigned* __restrict__ deg_out, unsigned* __restrict__ deg_in) {
    int e = blockIdx.x * blockDim.x + threadIdx.x;
    if (e < N_EDGES) {
        atomicAdd(&deg_out[src[e]], 1u);
        atomicAdd(&deg_in[dst[e]], 1u);
    }
}

__global__ void norm_kernel(const unsigned* __restrict__ deg_out, const unsigned* __restrict__ deg_in,
                            float* __restrict__ nsrc, float* __restrict__ ndst) {
    int i = blockIdx.x * blockDim.x + threadIdx.x;
    if (i < N_NODES) {
        unsigned o = deg_out[i]; if (o < 1u) o = 1u;
        unsigned d = deg_in[i];  if (d < 1u) d = 1u;
        nsrc[i] = rsqrtf((float)o);
        ndst[i] = rsqrtf((float)d);
    }
}

// ---------------- CSR build: exclusive scan of deg_in -> rowptr ----------------
__global__ __launch_bounds__(256) void scan_blocksum(const unsigned* __restrict__ deg,
                                                     unsigned* __restrict__ bsum) {
    __shared__ unsigned s[256];
    int b = blockIdx.x, t = threadIdx.x;
    int base = b * SCAN_CHUNK + t * 4;
    unsigned v = 0;
#pragma unroll
    for (int i = 0; i < 4; i++) { int idx = base + i; if (idx < N_NODES) v += deg[idx]; }
    s[t] = v; __syncthreads();
    for (int off = 128; off > 0; off >>= 1) {
        if (t < off) s[t] += s[t + off];
        __syncthreads();
    }
    if (t == 0) bsum[b] = s[0];
}

__global__ void scan_bsum(unsigned* __restrict__ bsum, int* __restrict__ rowptr) {
    __shared__ unsigned s[128];
    int t = threadIdx.x;
    if (t < SCAN_NB) s[t] = bsum[t];
    __syncthreads();
    if (t == 0) {
        unsigned run = 0;
        for (int i = 0; i < SCAN_NB; i++) { unsigned x = s[i]; s[i] = run; run += x; }
    }
    __syncthreads();
    if (t < SCAN_NB) bsum[t] = s[t];
    if (t == 0) rowptr[N_NODES] = N_EDGES;
}

__global__ __launch_bounds__(256) void scan_write(const unsigned* __restrict__ deg,
                                                  const unsigned* __restrict__ bsum,
                                                  int* __restrict__ rowptr) {
    __shared__ unsigned ts[256];
    int b = blockIdx.x, t = threadIdx.x;
    int base = b * SCAN_CHUNK + t * 4;
    unsigned v[4]; unsigned sum = 0;
#pragma unroll
    for (int i = 0; i < 4; i++) { int idx = base + i; v[i] = (idx < N_NODES) ? deg[idx] : 0u; sum += v[i]; }
    ts[t] = sum; __syncthreads();
    for (int off = 1; off < 256; off <<= 1) {
        unsigned add = (t >= off) ? ts[t - off] : 0u;
        __syncthreads();
        ts[t] += add;
        __syncthreads();
    }
    unsigned excl = (t == 0) ? 0u : ts[t - 1];
    unsigned run = bsum[b] + excl;
#pragma unroll
    for (int i = 0; i < 4; i++) {
        int idx = base + i;
        if (idx < N_NODES) rowptr[idx] = (int)run;
        run += v[i];
    }
}

__global__ void scatter_kernel(const int* __restrict__ src, const int* __restrict__ dst,
                               const int* __restrict__ rowptr, unsigned* __restrict__ cursor,
                               int* __restrict__ esrc) {
    int e = blockIdx.x * blockDim.x + threadIdx.x;
    if (e < N_EDGES) {
        int d = dst[e];
        unsigned r = atomicAdd(&cursor[d], 1u);
        esrc[rowptr[d] + r] = src[e];
    }
}

// ---------------- GEMM1: H = (X * nsrc) @ W1   [100000x512]@[512x128] ----------------
#define BM 64
#define BK 32
__global__ __launch_bounds__(256) void gemm1_kernel(const float* __restrict__ X,
                                                    const float* __restrict__ W,
                                                    const float* __restrict__ nsrc,
                                                    float* __restrict__ H) {
    __shared__ float Xs[BM][BK + 1];
    __shared__ float Ws[BK][FHID];
    const int bm = blockIdx.x * BM;
    const int t = threadIdx.x;
    const int ty = t >> 4;
    const int tx = t & 15;

    float acc[4][8];
#pragma unroll
    for (int i = 0; i < 4; i++)
#pragma unroll
        for (int j = 0; j < 8; j++) acc[i][j] = 0.f;

    for (int k0 = 0; k0 < FIN; k0 += BK) {
#pragma unroll
        for (int l = 0; l < 2; l++) {
            int idx = t + l * 256;
            int r = idx >> 3;
            int c4 = idx & 7;
            int row = bm + r;
            float4 v = make_float4(0.f, 0.f, 0.f, 0.f);
            if (row < N_NODES) {
                v = *(const float4*)(X + (size_t)row * FIN + k0 + c4 * 4);
                float s = nsrc[row];
                v.x *= s; v.y *= s; v.z *= s; v.w *= s;
            }
            Xs[r][c4 * 4 + 0] = v.x; Xs[r][c4 * 4 + 1] = v.y;
            Xs[r][c4 * 4 + 2] = v.z; Xs[r][c4 * 4 + 3] = v.w;
        }
#pragma unroll
        for (int l = 0; l < 4; l++) {
            int idx = t + l * 256;
            int r = idx >> 5;
            int c4 = idx & 31;
            float4 v = *(const float4*)(W + (size_t)(k0 + r) * FHID + c4 * 4);
            *(float4*)&Ws[r][c4 * 4] = v;
        }
        __syncthreads();
#pragma unroll
        for (int kk = 0; kk < BK; kk++) {
            float a[4], b[8];
#pragma unroll
            for (int i = 0; i < 4; i++) a[i] = Xs[ty * 4 + i][kk];
#pragma unroll
            for (int j = 0; j < 8; j++) b[j] = Ws[kk][tx * 8 + j];
#pragma unroll
            for (int i = 0; i < 4; i++)
#pragma unroll
                for (int j = 0; j < 8; j++)
                    acc[i][j] = fmaf(a[i], b[j], acc[i][j]);
        }
        __syncthreads();
    }
#pragma unroll
    for (int i = 0; i < 4; i++) {
        int row = bm + ty * 4 + i;
        if (row < N_NODES) {
#pragma unroll
            for (int j = 0; j < 8; j += 4) {
                float4 v = make_float4(acc[i][j], acc[i][j + 1], acc[i][j + 2], acc[i][j + 3]);
                *(float4*)(H + (size_t)row * FHID + tx * 8 + j) = v;
            }
        }
    }
}

// ---------------- SpMM1 gather + finish1 fused: X2 = relu(ndst * sum H[src] + b1) ----------------
__global__ __launch_bounds__(256) void spmm1_gather(const int* __restrict__ rowptr,
                                                    const int* __restrict__ esrc,
                                                    const float* __restrict__ H,
                                                    const float* __restrict__ ndst,
                                                    const float* __restrict__ b1,
                                                    float* __restrict__ X2) {
    int node = blockIdx.x * (blockDim.x >> 6) + (threadIdx.x >> 6);
    if (node >= N_NODES) return;
    int lane = threadIdx.x & 63;
    int beg = rowptr[node], end = rowptr[node + 1];
    float2 acc = make_float2(0.f, 0.f);
    int p = beg;
    for (; p + 1 < end; p += 2) {
        int s0 = esrc[p], s1 = esrc[p + 1];
        float2 v0 = *(const float2*)(H + (size_t)s0 * FHID + lane * 2);
        float2 v1 = *(const float2*)(H + (size_t)s1 * FHID + lane * 2);
        acc.x += v0.x + v1.x;
        acc.y += v0.y + v1.y;
    }
    if (p < end) {
        int s0 = esrc[p];
        float2 v0 = *(const float2*)(H + (size_t)s0 * FHID + lane * 2);
        acc.x += v0.x; acc.y += v0.y;
    }
    float nd = ndst[node];
    float2 b = *(const float2*)(b1 + lane * 2);
    float2 o;
    o.x = fmaxf(fmaf(acc.x, nd, b.x), 0.f);
    o.y = fmaxf(fmaf(acc.y, nd, b.y), 0.f);
    *(float2*)(X2 + (size_t)node * FHID + lane * 2) = o;
}

// ---------------- GEMM2: H2 = (X2 * nsrc) @ W2   [100000x128]@[128x40] ----------------
__global__ __launch_bounds__(320) void gemm2_kernel(const float* __restrict__ X2,
                                                    const float* __restrict__ W2,
                                                    const float* __restrict__ nsrc,
                                                    float* __restrict__ H2) {
    __shared__ float Ws[FHID][FOUT];
    __shared__ float Xs[32][FHID];
    const int t = threadIdx.x;
    const int bm = blockIdx.x * 32;
    for (int idx = t; idx < FHID * FOUT; idx += 320)
        Ws[idx / FOUT][idx % FOUT] = W2[idx];
    for (int idx = t; idx < 32 * FHID / 4; idx += 320) {
        int r = idx >> 5;
        int c4 = idx & 31;
        int row = bm + r;
        float4 v = make_float4(0.f, 0.f, 0.f, 0.f);
        if (row < N_NODES) {
            v = *(const float4*)(X2 + (size_t)row * FHID + c4 * 4);
            float s = nsrc[row];
            v.x *= s; v.y *= s; v.z *= s; v.w *= s;
        }
        *(float4*)&Xs[r][c4 * 4] = v;
    }
    __syncthreads();
    const int r0 = t / FOUT;
    const int c = t % FOUT;
    float acc[4] = {0.f, 0.f, 0.f, 0.f};
    for (int k = 0; k < FHID; k++) {
        float b = Ws[k][c];
#pragma unroll
        for (int i = 0; i < 4; i++)
            acc[i] = fmaf(Xs[r0 + i * 8][k], b, acc[i]);
    }
#pragma unroll
    for (int i = 0; i < 4; i++) {
        int row = bm + r0 + i * 8;
        if (row < N_NODES) H2[(size_t)row * FOUT + c] = acc[i];
    }
}

// ---------------- SpMM2 gather + finish2 fused: OUT = ndst * sum H2[src] + b2 ----------------
__global__ __launch_bounds__(256) void spmm2_gather(const int* __restrict__ rowptr,
                                                    const int* __restrict__ esrc,
                                                    const float* __restrict__ H2,
                                                    const float* __restrict__ ndst,
                                                    const float* __restrict__ b2,
                                                    float* __restrict__ OUT) {
    int node = blockIdx.x * (blockDim.x >> 6) + (threadIdx.x >> 6);
    if (node >= N_NODES) return;
    int lane = threadIdx.x & 63;
    int beg = rowptr[node], end = rowptr[node + 1];
    float acc = 0.f;
    int p = beg;
    for (; p + 1 < end; p += 2) {
        int s0 = esrc[p], s1 = esrc[p + 1];
        if (lane < FOUT) {
            float v0 = H2[(size_t)s0 * FOUT + lane];
            float v1 = H2[(size_t)s1 * FOUT + lane];
            acc += v0 + v1;
        }
    }
    if (p < end) {
        int s0 = esrc[p];
        if (lane < FOUT) acc += H2[(size_t)s0 * FOUT + lane];
    }
    if (lane < FOUT) {
        float nd = ndst[node];
        OUT[(size_t)node * FOUT + lane] = fmaf(acc, nd, b2[lane]);
    }
}

extern "C" void kernel_launch(void* const* d_in, const int* in_sizes, int n_in,
                              void* d_out, int out_size, void* d_ws, size_t ws_size,
                              hipStream_t stream) {
    const float* feat = (const float*)d_in[0];
    const int*   src  = (const int*)d_in[1];
    const int*   dst  = (const int*)d_in[2];
    const float* W1   = (const float*)d_in[3];
    const float* b1   = (const float*)d_in[4];
    const float* W2   = (const float*)d_in[5];
    const float* b2   = (const float*)d_in[6];
    float* out = (float*)d_out;

    char* ws = (char*)d_ws;
    const size_t SZ_BIG = (size_t)N_NODES * FHID * sizeof(float);   // 51.2 MB
    float* bufA = (float*)ws;                    // H1 (gemm1 out), then H2 (gemm2 out)
    float* bufB = (float*)(ws + SZ_BIG);         // X2 (spmm1 out)
    char*  small = ws + 2 * SZ_BIG;
    const size_t SSTRIDE = 401408;               // 512B-aligned, >= 400004 B
    unsigned* degO   = (unsigned*)(small);
    unsigned* degI   = (unsigned*)(small + SSTRIDE);
    unsigned* cursor = (unsigned*)(small + 2 * SSTRIDE);
    float*    nsrc   = (float*)(small + 3 * SSTRIDE);
    float*    ndst   = (float*)(small + 4 * SSTRIDE);
    int*      rowptr = (int*)(small + 5 * SSTRIDE);
    unsigned* bsum   = (unsigned*)(small + 6 * SSTRIDE);
    int*      esrc   = (int*)(small + 7 * SSTRIDE);   // 6.4 MB

    hipMemsetAsync(small, 0, 3 * SSTRIDE, stream);   // degO, degI, cursor

    deg_kernel<<<(N_EDGES + 255) / 256, 256, 0, stream>>>(src, dst, degO, degI);
    norm_kernel<<<(N_NODES + 255) / 256, 256, 0, stream>>>(degO, degI, nsrc, ndst);
    scan_blocksum<<<SCAN_NB, 256, 0, stream>>>(degI, bsum);
    scan_bsum<<<1, 128, 0, stream>>>(bsum, rowptr);
    scan_write<<<SCAN_NB, 256, 0, stream>>>(degI, bsum, rowptr);
    scatter_kernel<<<(N_EDGES + 255) / 256, 256, 0, stream>>>(src, dst, rowptr, cursor, esrc);

    gemm1_kernel<<<(N_NODES + BM - 1) / BM, 256, 0, stream>>>(feat, W1, nsrc, bufA);      // H1 -> bufA
    spmm1_gather<<<(N_NODES + 3) / 4, 256, 0, stream>>>(rowptr, esrc, bufA, ndst, b1, bufB); // X2 -> bufB
    gemm2_kernel<<<(N_NODES + 31) / 32, 320, 0, stream>>>(bufB, W2, nsrc, bufA);          // H2 -> bufA
    spmm2_gather<<<(N_NODES + 3) / 4, 256, 0, stream>>>(rowptr, esrc, bufA, ndst, b2, out);
}

// Round 3
// 575.418 us; speedup vs baseline: 3.4299x; 1.2227x over previous
//
#include <hip/hip_runtime.h>

#define N_NODES 100000
#define N_EDGES 1600000
#define FIN 512
#define FHID 128
#define FOUT 40

#define SCAN_CHUNK 1024
#define SCAN_NB ((N_NODES + SCAN_CHUNK - 1) / SCAN_CHUNK)   // 98

typedef __attribute__((ext_vector_type(8))) short short8;   // 8 bf16 (4 VGPR)
typedef __attribute__((ext_vector_type(4))) float f32x4;    // MFMA acc

static __device__ inline unsigned short f2bf(float f) {
    unsigned x = __float_as_uint(f);
    unsigned r = (x + 0x7fffu + ((x >> 16) & 1u)) >> 16;    // RNE
    return (unsigned short)r;
}

// ---------------- degree ----------------
__global__ void deg_kernel(const int* __restrict__ src, const int* __restrict__ dst,
                           unsigned* __restrict__ deg_out, unsigned* __restrict__ deg_in) {
    int e = blockIdx.x * blockDim.x + threadIdx.x;
    if (e < N_EDGES) {
        atomicAdd(&deg_out[src[e]], 1u);
        atomicAdd(&deg_in[dst[e]], 1u);
    }
}

__global__ void norm_kernel(const unsigned* __restrict__ deg_out, const unsigned* __restrict__ deg_in,
                            float* __restrict__ nsrc, float* __restrict__ ndst) {
    int i = blockIdx.x * blockDim.x + threadIdx.x;
    if (i < N_NODES) {
        unsigned o = deg_out[i]; if (o < 1u) o = 1u;
        unsigned d = deg_in[i];  if (d < 1u) d = 1u;
        nsrc[i] = rsqrtf((float)o);
        ndst[i] = rsqrtf((float)d);
    }
}

// ---------------- CSR build: exclusive scan of deg_in -> rowptr ----------------
__global__ __launch_bounds__(256) void scan_blocksum(const unsigned* __restrict__ deg,
                                                     unsigned* __restrict__ bsum) {
    __shared__ unsigned s[256];
    int b = blockIdx.x, t = threadIdx.x;
    int base = b * SCAN_CHUNK + t * 4;
    unsigned v = 0;
#pragma unroll
    for (int i = 0; i < 4; i++) { int idx = base + i; if (idx < N_NODES) v += deg[idx]; }
    s[t] = v; __syncthreads();
    for (int off = 128; off > 0; off >>= 1) {
        if (t < off) s[t] += s[t + off];
        __syncthreads();
    }
    if (t == 0) bsum[b] = s[0];
}

__global__ void scan_bsum(unsigned* __restrict__ bsum, int* __restrict__ rowptr) {
    __shared__ unsigned s[128];
    int t = threadIdx.x;
    if (t < SCAN_NB) s[t] = bsum[t];
    __syncthreads();
    if (t == 0) {
        unsigned run = 0;
        for (int i = 0; i < SCAN_NB; i++) { unsigned x = s[i]; s[i] = run; run += x; }
    }
    __syncthreads();
    if (t < SCAN_NB) bsum[t] = s[t];
    if (t == 0) rowptr[N_NODES] = N_EDGES;
}

__global__ __launch_bounds__(256) void scan_write(const unsigned* __restrict__ deg,
                                                  const unsigned* __restrict__ bsum,
                                                  int* __restrict__ rowptr) {
    __shared__ unsigned ts[256];
    int b = blockIdx.x, t = threadIdx.x;
    int base = b * SCAN_CHUNK + t * 4;
    unsigned v[4]; unsigned sum = 0;
#pragma unroll
    for (int i = 0; i < 4; i++) { int idx = base + i; v[i] = (idx < N_NODES) ? deg[idx] : 0u; sum += v[i]; }
    ts[t] = sum; __syncthreads();
    for (int off = 1; off < 256; off <<= 1) {
        unsigned add = (t >= off) ? ts[t - off] : 0u;
        __syncthreads();
        ts[t] += add;
        __syncthreads();
    }
    unsigned excl = (t == 0) ? 0u : ts[t - 1];
    unsigned run = bsum[b] + excl;
#pragma unroll
    for (int i = 0; i < 4; i++) {
        int idx = base + i;
        if (idx < N_NODES) rowptr[idx] = (int)run;
        run += v[i];
    }
}

__global__ void scatter_kernel(const int* __restrict__ src, const int* __restrict__ dst,
                               const int* __restrict__ rowptr, unsigned* __restrict__ cursor,
                               int* __restrict__ esrc) {
    int e = blockIdx.x * blockDim.x + threadIdx.x;
    if (e < N_EDGES) {
        int d = dst[e];
        unsigned r = atomicAdd(&cursor[d], 1u);
        esrc[rowptr[d] + r] = src[e];
    }
}

// ---------------- W1 -> bf16 transposed: Wt[n][k] = bf16(W1[k][n]) ----------------
__global__ __launch_bounds__(256) void wcvt_kernel(const float* __restrict__ W1,
                                                   unsigned short* __restrict__ Wt) {
    int j = blockIdx.x * blockDim.x + threadIdx.x;   // j = k*128 + n
    if (j < FIN * FHID) {
        int k = j >> 7;
        int n = j & 127;
        Wt[n * FIN + k] = f2bf(W1[j]);
    }
}

// ---------------- GEMM1 (bf16 MFMA): H = bf16(X*nsrc) @ bf16(W1)  [100000x512]@[512x128]
// BM=64 rows x BN=128 cols per block, BK=64, 4 waves: wave w -> rows w*16..w*16+15.
// LDS tiles XOR-swizzled: 16B slot index ^= (row&7); 128B row stride.
__global__ __launch_bounds__(256) void gemm1_mfma(const float* __restrict__ X,
                                                  const unsigned short* __restrict__ Wt,
                                                  const float* __restrict__ nsrc,
                                                  float* __restrict__ H) {
    __shared__ __align__(16) unsigned short Xs[64 * 64];    // 8KB  [row][k]
    __shared__ __align__(16) unsigned short Bs[128 * 64];   // 16KB [col][k]
    const int t = threadIdx.x;
    const int bm = blockIdx.x * 64;
    const int w = t >> 6;          // wave 0..3
    const int l = t & 63;
    const int r = l & 15;          // row/col within 16-tile
    const int kg = l >> 4;         // k-group 0..3 (8 bf16 each)

    f32x4 acc[8];
#pragma unroll
    for (int c = 0; c < 8; c++) acc[c] = (f32x4){0.f, 0.f, 0.f, 0.f};

    for (int s = 0; s < FIN / 64; ++s) {
        const int k0 = s * 64;
        // ---- stage A: 512 tasks (row 0..63, slot 0..7), 2 per thread
#pragma unroll
        for (int i = 0; i < 2; i++) {
            int idx = t + i * 256;
            int row = idx >> 3;
            int slot = idx & 7;
            int grow = bm + row;
            unsigned short u[8];
            if (grow < N_NODES) {
                const float* p = X + (size_t)grow * FIN + k0 + slot * 8;
                float4 v0 = *(const float4*)(p);
                float4 v1 = *(const float4*)(p + 4);
                float sc = nsrc[grow];
                u[0] = f2bf(v0.x * sc); u[1] = f2bf(v0.y * sc);
                u[2] = f2bf(v0.z * sc); u[3] = f2bf(v0.w * sc);
                u[4] = f2bf(v1.x * sc); u[5] = f2bf(v1.y * sc);
                u[6] = f2bf(v1.z * sc); u[7] = f2bf(v1.w * sc);
            } else {
#pragma unroll
                for (int q = 0; q < 8; q++) u[q] = 0;
            }
            uint4 packed;
            packed.x = (unsigned)u[0] | ((unsigned)u[1] << 16);
            packed.y = (unsigned)u[2] | ((unsigned)u[3] << 16);
            packed.z = (unsigned)u[4] | ((unsigned)u[5] << 16);
            packed.w = (unsigned)u[6] | ((unsigned)u[7] << 16);
            *(uint4*)&Xs[row * 64 + ((slot ^ (row & 7)) * 8)] = packed;
        }
        // ---- stage B: 1024 tasks (col 0..127, slot 0..7), 4 per thread
#pragma unroll
        for (int i = 0; i < 4; i++) {
            int idx = t + i * 256;
            int col = idx >> 3;
            int slot = idx & 7;
            uint4 packed = *(const uint4*)&Wt[col * FIN + k0 + slot * 8];
            *(uint4*)&Bs[col * 64 + ((slot ^ (col & 7)) * 8)] = packed;
        }
        __syncthreads();
        // ---- compute: per wave 2 A-frags + 8 col-tiles x 2 k-halves
        const int arow = w * 16 + r;
        short8 a0 = *(const short8*)&Xs[arow * 64 + (((0 + kg) ^ (r & 7)) * 8)];
        short8 a1 = *(const short8*)&Xs[arow * 64 + (((4 + kg) ^ (r & 7)) * 8)];
#pragma unroll
        for (int c = 0; c < 8; c++) {
            const int brow = c * 16 + r;
            short8 b0 = *(const short8*)&Bs[brow * 64 + (((0 + kg) ^ (r & 7)) * 8)];
            short8 b1 = *(const short8*)&Bs[brow * 64 + (((4 + kg) ^ (r & 7)) * 8)];
            acc[c] = __builtin_amdgcn_mfma_f32_16x16x32_bf16(a0, b0, acc[c], 0, 0, 0);
            acc[c] = __builtin_amdgcn_mfma_f32_16x16x32_bf16(a1, b1, acc[c], 0, 0, 0);
        }
        __syncthreads();
    }
    // ---- epilogue: C/D layout col=lane&15, row=(lane>>4)*4+reg
#pragma unroll
    for (int j = 0; j < 4; j++) {
        int grow = bm + w * 16 + kg * 4 + j;
        if (grow < N_NODES) {
#pragma unroll
            for (int c = 0; c < 8; c++)
                H[(size_t)grow * FHID + c * 16 + r] = acc[c][j];
        }
    }
}

// ---------------- SpMM1 gather + finish1 fused: X2 = relu(ndst * sum H[src] + b1) ----------------
__global__ __launch_bounds__(256) void spmm1_gather(const int* __restrict__ rowptr,
                                                    const int* __restrict__ esrc,
                                                    const float* __restrict__ H,
                                                    const float* __restrict__ ndst,
                                                    const float* __restrict__ b1,
                                                    float* __restrict__ X2) {
    int node = blockIdx.x * (blockDim.x >> 6) + (threadIdx.x >> 6);
    if (node >= N_NODES) return;
    int lane = threadIdx.x & 63;
    int beg = rowptr[node], end = rowptr[node + 1];
    float2 acc = make_float2(0.f, 0.f);
    int p = beg;
    for (; p + 1 < end; p += 2) {
        int s0 = esrc[p], s1 = esrc[p + 1];
        float2 v0 = *(const float2*)(H + (size_t)s0 * FHID + lane * 2);
        float2 v1 = *(const float2*)(H + (size_t)s1 * FHID + lane * 2);
        acc.x += v0.x + v1.x;
        acc.y += v0.y + v1.y;
    }
    if (p < end) {
        int s0 = esrc[p];
        float2 v0 = *(const float2*)(H + (size_t)s0 * FHID + lane * 2);
        acc.x += v0.x; acc.y += v0.y;
    }
    float nd = ndst[node];
    float2 b = *(const float2*)(b1 + lane * 2);
    float2 o;
    o.x = fmaxf(fmaf(acc.x, nd, b.x), 0.f);
    o.y = fmaxf(fmaf(acc.y, nd, b.y), 0.f);
    *(float2*)(X2 + (size_t)node * FHID + lane * 2) = o;
}

// ---------------- GEMM2: H2 = (X2 * nsrc) @ W2   [100000x128]@[128x40] ----------------
__global__ __launch_bounds__(320) void gemm2_kernel(const float* __restrict__ X2,
                                                    const float* __restrict__ W2,
                                                    const float* __restrict__ nsrc,
                                                    float* __restrict__ H2) {
    __shared__ float Ws[FHID][FOUT];
    __shared__ float Xs[32][FHID];
    const int t = threadIdx.x;
    const int bm = blockIdx.x * 32;
    for (int idx = t; idx < FHID * FOUT; idx += 320)
        Ws[idx / FOUT][idx % FOUT] = W2[idx];
    for (int idx = t; idx < 32 * FHID / 4; idx += 320) {
        int r = idx >> 5;
        int c4 = idx & 31;
        int row = bm + r;
        float4 v = make_float4(0.f, 0.f, 0.f, 0.f);
        if (row < N_NODES) {
            v = *(const float4*)(X2 + (size_t)row * FHID + c4 * 4);
            float s = nsrc[row];
            v.x *= s; v.y *= s; v.z *= s; v.w *= s;
        }
        *(float4*)&Xs[r][c4 * 4] = v;
    }
    __syncthreads();
    const int r0 = t / FOUT;
    const int c = t % FOUT;
    float acc[4] = {0.f, 0.f, 0.f, 0.f};
    for (int k = 0; k < FHID; k++) {
        float b = Ws[k][c];
#pragma unroll
        for (int i = 0; i < 4; i++)
            acc[i] = fmaf(Xs[r0 + i * 8][k], b, acc[i]);
    }
#pragma unroll
    for (int i = 0; i < 4; i++) {
        int row = bm + r0 + i * 8;
        if (row < N_NODES) H2[(size_t)row * FOUT + c] = acc[i];
    }
}

// ---------------- SpMM2 gather + finish2 fused: OUT = ndst * sum H2[src] + b2 ----------------
__global__ __launch_bounds__(256) void spmm2_gather(const int* __restrict__ rowptr,
                                                    const int* __restrict__ esrc,
                                                    const float* __restrict__ H2,
                                                    const float* __restrict__ ndst,
                                                    const float* __restrict__ b2,
                                                    float* __restrict__ OUT) {
    int node = blockIdx.x * (blockDim.x >> 6) + (threadIdx.x >> 6);
    if (node >= N_NODES) return;
    int lane = threadIdx.x & 63;
    int beg = rowptr[node], end = rowptr[node + 1];
    float acc = 0.f;
    int p = beg;
    for (; p + 1 < end; p += 2) {
        int s0 = esrc[p], s1 = esrc[p + 1];
        if (lane < FOUT) {
            float v0 = H2[(size_t)s0 * FOUT + lane];
            float v1 = H2[(size_t)s1 * FOUT + lane];
            acc += v0 + v1;
        }
    }
    if (p < end) {
        int s0 = esrc[p];
        if (lane < FOUT) acc += H2[(size_t)s0 * FOUT + lane];
    }
    if (lane < FOUT) {
        float nd = ndst[node];
        OUT[(size_t)node * FOUT + lane] = fmaf(acc, nd, b2[lane]);
    }
}

extern "C" void kernel_launch(void* const* d_in, const int* in_sizes, int n_in,
                              void* d_out, int out_size, void* d_ws, size_t ws_size,
                              hipStream_t stream) {
    const float* feat = (const float*)d_in[0];
    const int*   src  = (const int*)d_in[1];
    const int*   dst  = (const int*)d_in[2];
    const float* W1   = (const float*)d_in[3];
    const float* b1   = (const float*)d_in[4];
    const float* W2   = (const float*)d_in[5];
    const float* b2   = (const float*)d_in[6];
    float* out = (float*)d_out;

    char* ws = (char*)d_ws;
    const size_t SZ_BIG = (size_t)N_NODES * FHID * sizeof(float);   // 51.2 MB
    float* bufA = (float*)ws;                    // H1 (gemm1 out), then H2 (gemm2 out)
    float* bufB = (float*)(ws + SZ_BIG);         // X2 (spmm1 out)
    char*  small = ws + 2 * SZ_BIG;
    const size_t SSTRIDE = 401408;               // 512B-aligned
    unsigned* degO   = (unsigned*)(small);
    unsigned* degI   = (unsigned*)(small + SSTRIDE);
    unsigned* cursor = (unsigned*)(small + 2 * SSTRIDE);
    float*    nsrc   = (float*)(small + 3 * SSTRIDE);
    float*    ndst   = (float*)(small + 4 * SSTRIDE);
    int*      rowptr = (int*)(small + 5 * SSTRIDE);
    unsigned* bsum   = (unsigned*)(small + 6 * SSTRIDE);
    unsigned short* Wt = (unsigned short*)(small + 7 * SSTRIDE);   // 128KB bf16 W1^T
    int*      esrc   = (int*)(small + 8 * SSTRIDE);                // 6.4 MB

    hipMemsetAsync(small, 0, 3 * SSTRIDE, stream);   // degO, degI, cursor

    deg_kernel<<<(N_EDGES + 255) / 256, 256, 0, stream>>>(src, dst, degO, degI);
    norm_kernel<<<(N_NODES + 255) / 256, 256, 0, stream>>>(degO, degI, nsrc, ndst);
    scan_blocksum<<<SCAN_NB, 256, 0, stream>>>(degI, bsum);
    scan_bsum<<<1, 128, 0, stream>>>(bsum, rowptr);
    scan_write<<<SCAN_NB, 256, 0, stream>>>(degI, bsum, rowptr);
    scatter_kernel<<<(N_EDGES + 255) / 256, 256, 0, stream>>>(src, dst, rowptr, cursor, esrc);
    wcvt_kernel<<<(FIN * FHID + 255) / 256, 256, 0, stream>>>(W1, Wt);

    gemm1_mfma<<<(N_NODES + 63) / 64, 256, 0, stream>>>(feat, Wt, nsrc, bufA);               // H1 -> bufA
    spmm1_gather<<<(N_NODES + 3) / 4, 256, 0, stream>>>(rowptr, esrc, bufA, ndst, b1, bufB); // X2 -> bufB
    gemm2_kernel<<<(N_NODES + 31) / 32, 320, 0, stream>>>(bufB, W2, nsrc, bufA);             // H2 -> bufA
    spmm2_gather<<<(N_NODES + 3) / 4, 256, 0, stream>>>(rowptr, esrc, bufA, ndst, b2, out);
}

// Round 4
// 429.761 us; speedup vs baseline: 4.5924x; 1.3389x over previous
//
#include <hip/hip_runtime.h>

#define N_NODES 100000
#define N_EDGES 1600000
#define FIN 512
#define FHID 128
#define FOUT 40

#define SCAN_CHUNK 1024
#define SCAN_NB ((N_NODES + SCAN_CHUNK - 1) / SCAN_CHUNK)   // 98

// CSR-build histogram geometry
#define NRANGE 8
#define RANGE_SZ 12500          // 8 * 12500 = 100000; 50KB LDS u32
#define GH 16                   // edge slices per task
#define EDGE_SLICE (N_EDGES / GH)   // 100000

typedef __attribute__((ext_vector_type(8))) short short8;   // 8 bf16 (4 VGPR)
typedef __attribute__((ext_vector_type(4))) float f32x4;    // MFMA acc

static __device__ inline unsigned short f2bf(float f) {
    unsigned x = __float_as_uint(f);
    unsigned r = (x + 0x7fffu + ((x >> 16) & 1u)) >> 16;    // RNE
    return (unsigned short)r;
}

// ---------------- deg_hist: LDS-privatized degree histograms, no global atomics ----
// task = blockIdx.x / GH in [0,16): a = task/NRANGE (0=src,1=dst), rg = task%NRANGE.
// scratch[((task)*GH + g)*RANGE_SZ + off] = count of value rg*RANGE_SZ+off in slice g.
__global__ __launch_bounds__(256) void deg_hist(const int* __restrict__ src,
                                                const int* __restrict__ dst,
                                                unsigned* __restrict__ scratch) {
    __shared__ unsigned hist[RANGE_SZ];
    const int task = blockIdx.x / GH;
    const int g = blockIdx.x % GH;
    const int a = task / NRANGE;
    const int rg = task % NRANGE;
    const int lo = rg * RANGE_SZ;
    const int t = threadIdx.x;
    for (int i = t; i < RANGE_SZ; i += 256) hist[i] = 0;
    __syncthreads();
    const int* arr = a ? dst : src;
    const int4* p = (const int4*)(arr + g * EDGE_SLICE);
    for (int i = t; i < EDGE_SLICE / 4; i += 256) {
        int4 v = p[i];
        int x;
        x = v.x - lo; if ((unsigned)x < RANGE_SZ) atomicAdd(&hist[x], 1u);
        x = v.y - lo; if ((unsigned)x < RANGE_SZ) atomicAdd(&hist[x], 1u);
        x = v.z - lo; if ((unsigned)x < RANGE_SZ) atomicAdd(&hist[x], 1u);
        x = v.w - lo; if ((unsigned)x < RANGE_SZ) atomicAdd(&hist[x], 1u);
    }
    __syncthreads();
    unsigned* out = scratch + ((size_t)task * GH + g) * RANGE_SZ;
    for (int i = t; i < RANGE_SZ; i += 256) out[i] = hist[i];
}

// ---------------- deg_reduce: sum slices -> degI; fused norms ----------------
__global__ __launch_bounds__(256) void deg_reduce(const unsigned* __restrict__ scratch,
                                                  float* __restrict__ nsrc,
                                                  float* __restrict__ ndst,
                                                  unsigned* __restrict__ degI) {
    int i = blockIdx.x * 256 + threadIdx.x;
    if (i >= N_NODES) return;
    const int rg = i / RANGE_SZ;
    const int off = i % RANGE_SZ;
    const unsigned* ps = scratch + ((size_t)rg * GH) * RANGE_SZ + off;
    const unsigned* pd = scratch + ((size_t)(NRANGE + rg) * GH) * RANGE_SZ + off;
    unsigned so = 0, si = 0;
#pragma unroll
    for (int g = 0; g < GH; g++) {
        so += ps[(size_t)g * RANGE_SZ];
        si += pd[(size_t)g * RANGE_SZ];
    }
    degI[i] = si;
    nsrc[i] = rsqrtf((float)(so < 1u ? 1u : so));
    ndst[i] = rsqrtf((float)(si < 1u ? 1u : si));
}

// ---------------- CSR rowptr: exclusive scan of degI ----------------
__global__ __launch_bounds__(256) void scan_blocksum(const unsigned* __restrict__ deg,
                                                     unsigned* __restrict__ bsum) {
    __shared__ unsigned s[256];
    int b = blockIdx.x, t = threadIdx.x;
    int base = b * SCAN_CHUNK + t * 4;
    unsigned v = 0;
#pragma unroll
    for (int i = 0; i < 4; i++) { int idx = base + i; if (idx < N_NODES) v += deg[idx]; }
    s[t] = v; __syncthreads();
    for (int off = 128; off > 0; off >>= 1) {
        if (t < off) s[t] += s[t + off];
        __syncthreads();
    }
    if (t == 0) bsum[b] = s[0];
}

__global__ void scan_bsum(unsigned* __restrict__ bsum, int* __restrict__ rowptr) {
    __shared__ unsigned s[128];
    int t = threadIdx.x;
    if (t < SCAN_NB) s[t] = bsum[t];
    __syncthreads();
    if (t == 0) {
        unsigned run = 0;
        for (int i = 0; i < SCAN_NB; i++) { unsigned x = s[i]; s[i] = run; run += x; }
    }
    __syncthreads();
    if (t < SCAN_NB) bsum[t] = s[t];
    if (t == 0) rowptr[N_NODES] = N_EDGES;
}

__global__ __launch_bounds__(256) void scan_write(const unsigned* __restrict__ deg,
                                                  const unsigned* __restrict__ bsum,
                                                  int* __restrict__ rowptr) {
    __shared__ unsigned ts[256];
    int b = blockIdx.x, t = threadIdx.x;
    int base = b * SCAN_CHUNK + t * 4;
    unsigned v[4]; unsigned sum = 0;
#pragma unroll
    for (int i = 0; i < 4; i++) { int idx = base + i; v[i] = (idx < N_NODES) ? deg[idx] : 0u; sum += v[i]; }
    ts[t] = sum; __syncthreads();
    for (int off = 1; off < 256; off <<= 1) {
        unsigned add = (t >= off) ? ts[t - off] : 0u;
        __syncthreads();
        ts[t] += add;
        __syncthreads();
    }
    unsigned excl = (t == 0) ? 0u : ts[t - 1];
    unsigned run = bsum[b] + excl;
#pragma unroll
    for (int i = 0; i < 4; i++) {
        int idx = base + i;
        if (idx < N_NODES) rowptr[idx] = (int)run;
        run += v[i];
    }
}

// ---------------- mkbase: dst-half scratch counts -> per-(slice,node) CSR bases ----
__global__ __launch_bounds__(256) void mkbase(unsigned* __restrict__ scratch,
                                              const int* __restrict__ rowptr) {
    int i = blockIdx.x * 256 + threadIdx.x;
    if (i >= N_NODES) return;
    const int rg = i / RANGE_SZ;
    const int off = i % RANGE_SZ;
    unsigned* pd = scratch + ((size_t)(NRANGE + rg) * GH) * RANGE_SZ + off;
    unsigned run = (unsigned)rowptr[i];
#pragma unroll
    for (int g = 0; g < GH; g++) {
        unsigned c = pd[(size_t)g * RANGE_SZ];
        pd[(size_t)g * RANGE_SZ] = run;
        run += c;
    }
}

// ---------------- scatter2: CSR slot assignment via LDS cursors only ----------------
__global__ __launch_bounds__(256) void scatter2(const int* __restrict__ src,
                                                const int* __restrict__ dst,
                                                const unsigned* __restrict__ scratch,
                                                int* __restrict__ esrc) {
    __shared__ unsigned cur[RANGE_SZ];
    const int rg = blockIdx.x / GH;
    const int g = blockIdx.x % GH;
    const int lo = rg * RANGE_SZ;
    const int t = threadIdx.x;
    const unsigned* base = scratch + ((size_t)(NRANGE + rg) * GH + g) * RANGE_SZ;
    for (int i = t; i < RANGE_SZ; i += 256) cur[i] = base[i];
    __syncthreads();
    const int4* pd = (const int4*)(dst + g * EDGE_SLICE);
    const int4* ps = (const int4*)(src + g * EDGE_SLICE);
    for (int i = t; i < EDGE_SLICE / 4; i += 256) {
        int4 d4 = pd[i];
        int4 s4 = ps[i];
        int x;
        x = d4.x - lo; if ((unsigned)x < RANGE_SZ) esrc[atomicAdd(&cur[x], 1u)] = s4.x;
        x = d4.y - lo; if ((unsigned)x < RANGE_SZ) esrc[atomicAdd(&cur[x], 1u)] = s4.y;
        x = d4.z - lo; if ((unsigned)x < RANGE_SZ) esrc[atomicAdd(&cur[x], 1u)] = s4.z;
        x = d4.w - lo; if ((unsigned)x < RANGE_SZ) esrc[atomicAdd(&cur[x], 1u)] = s4.w;
    }
}

// ---------------- W1 -> bf16 transposed: Wt[n][k] = bf16(W1[k][n]) ----------------
__global__ __launch_bounds__(256) void wcvt_kernel(const float* __restrict__ W1,
                                                   unsigned short* __restrict__ Wt) {
    int j = blockIdx.x * blockDim.x + threadIdx.x;   // j = k*128 + n
    if (j < FIN * FHID) {
        int k = j >> 7;
        int n = j & 127;
        Wt[n * FIN + k] = f2bf(W1[j]);
    }
}

// ---------------- GEMM1 (bf16 MFMA): H = bf16(X*nsrc) @ bf16(W1), H stored bf16 ----
// BM=64 x BN=128, BK=64, 4 waves. LDS XOR-swizzle: 16B slot ^= (row&7).
__global__ __launch_bounds__(256) void gemm1_mfma(const float* __restrict__ X,
                                                  const unsigned short* __restrict__ Wt,
                                                  const float* __restrict__ nsrc,
                                                  unsigned short* __restrict__ H) {
    __shared__ __align__(16) unsigned short Xs[64 * 64];    // 8KB  [row][k]
    __shared__ __align__(16) unsigned short Bs[128 * 64];   // 16KB [col][k]
    const int t = threadIdx.x;
    const int bm = blockIdx.x * 64;
    const int w = t >> 6;
    const int l = t & 63;
    const int r = l & 15;
    const int kg = l >> 4;

    f32x4 acc[8];
#pragma unroll
    for (int c = 0; c < 8; c++) acc[c] = (f32x4){0.f, 0.f, 0.f, 0.f};

    for (int s = 0; s < FIN / 64; ++s) {
        const int k0 = s * 64;
#pragma unroll
        for (int i = 0; i < 2; i++) {
            int idx = t + i * 256;
            int row = idx >> 3;
            int slot = idx & 7;
            int grow = bm + row;
            unsigned short u[8];
            if (grow < N_NODES) {
                const float* p = X + (size_t)grow * FIN + k0 + slot * 8;
                float4 v0 = *(const float4*)(p);
                float4 v1 = *(const float4*)(p + 4);
                float sc = nsrc[grow];
                u[0] = f2bf(v0.x * sc); u[1] = f2bf(v0.y * sc);
                u[2] = f2bf(v0.z * sc); u[3] = f2bf(v0.w * sc);
                u[4] = f2bf(v1.x * sc); u[5] = f2bf(v1.y * sc);
                u[6] = f2bf(v1.z * sc); u[7] = f2bf(v1.w * sc);
            } else {
#pragma unroll
                for (int q = 0; q < 8; q++) u[q] = 0;
            }
            uint4 packed;
            packed.x = (unsigned)u[0] | ((unsigned)u[1] << 16);
            packed.y = (unsigned)u[2] | ((unsigned)u[3] << 16);
            packed.z = (unsigned)u[4] | ((unsigned)u[5] << 16);
            packed.w = (unsigned)u[6] | ((unsigned)u[7] << 16);
            *(uint4*)&Xs[row * 64 + ((slot ^ (row & 7)) * 8)] = packed;
        }
#pragma unroll
        for (int i = 0; i < 4; i++) {
            int idx = t + i * 256;
            int col = idx >> 3;
            int slot = idx & 7;
            uint4 packed = *(const uint4*)&Wt[col * FIN + k0 + slot * 8];
            *(uint4*)&Bs[col * 64 + ((slot ^ (col & 7)) * 8)] = packed;
        }
        __syncthreads();
        const int arow = w * 16 + r;
        short8 a0 = *(const short8*)&Xs[arow * 64 + (((0 + kg) ^ (r & 7)) * 8)];
        short8 a1 = *(const short8*)&Xs[arow * 64 + (((4 + kg) ^ (r & 7)) * 8)];
#pragma unroll
        for (int c = 0; c < 8; c++) {
            const int brow = c * 16 + r;
            short8 b0 = *(const short8*)&Bs[brow * 64 + (((0 + kg) ^ (r & 7)) * 8)];
            short8 b1 = *(const short8*)&Bs[brow * 64 + (((4 + kg) ^ (r & 7)) * 8)];
            acc[c] = __builtin_amdgcn_mfma_f32_16x16x32_bf16(a0, b0, acc[c], 0, 0, 0);
            acc[c] = __builtin_amdgcn_mfma_f32_16x16x32_bf16(a1, b1, acc[c], 0, 0, 0);
        }
        __syncthreads();
    }
    // epilogue: C/D layout col=lane&15, row=(lane>>4)*4+reg; store bf16
#pragma unroll
    for (int j = 0; j < 4; j++) {
        int grow = bm + w * 16 + kg * 4 + j;
        if (grow < N_NODES) {
#pragma unroll
            for (int c = 0; c < 8; c++)
                H[(size_t)grow * FHID + c * 16 + r] = f2bf(acc[c][j]);
        }
    }
}

// ---------------- SpMM1 gather (bf16 H) + finish1: X2 = relu(ndst * sum H[src] + b1) ----
__global__ __launch_bounds__(256) void spmm1_gather(const int* __restrict__ rowptr,
                                                    const int* __restrict__ esrc,
                                                    const unsigned* __restrict__ H,   // bf16x2
                                                    const float* __restrict__ ndst,
                                                    const float* __restrict__ b1,
                                                    float* __restrict__ X2) {
    int node = blockIdx.x * (blockDim.x >> 6) + (threadIdx.x >> 6);
    if (node >= N_NODES) return;
    int lane = threadIdx.x & 63;
    int beg = rowptr[node], end = rowptr[node + 1];
    float2 acc = make_float2(0.f, 0.f);
    int p = beg;
    for (; p + 1 < end; p += 2) {
        int s0 = esrc[p], s1 = esrc[p + 1];
        unsigned u0 = H[(size_t)s0 * (FHID / 2) + lane];
        unsigned u1 = H[(size_t)s1 * (FHID / 2) + lane];
        acc.x += __uint_as_float(u0 << 16) + __uint_as_float(u1 << 16);
        acc.y += __uint_as_float(u0 & 0xffff0000u) + __uint_as_float(u1 & 0xffff0000u);
    }
    if (p < end) {
        int s0 = esrc[p];
        unsigned u0 = H[(size_t)s0 * (FHID / 2) + lane];
        acc.x += __uint_as_float(u0 << 16);
        acc.y += __uint_as_float(u0 & 0xffff0000u);
    }
    float nd = ndst[node];
    float2 b = *(const float2*)(b1 + lane * 2);
    float2 o;
    o.x = fmaxf(fmaf(acc.x, nd, b.x), 0.f);
    o.y = fmaxf(fmaf(acc.y, nd, b.y), 0.f);
    *(float2*)(X2 + (size_t)node * FHID + lane * 2) = o;
}

// ---------------- GEMM2: H2 = (X2 * nsrc) @ W2   [100000x128]@[128x40] ----------------
__global__ __launch_bounds__(320) void gemm2_kernel(const float* __restrict__ X2,
                                                    const float* __restrict__ W2,
                                                    const float* __restrict__ nsrc,
                                                    float* __restrict__ H2) {
    __shared__ float Ws[FHID][FOUT];
    __shared__ float Xs[32][FHID];
    const int t = threadIdx.x;
    const int bm = blockIdx.x * 32;
    for (int idx = t; idx < FHID * FOUT; idx += 320)
        Ws[idx / FOUT][idx % FOUT] = W2[idx];
    for (int idx = t; idx < 32 * FHID / 4; idx += 320) {
        int r = idx >> 5;
        int c4 = idx & 31;
        int row = bm + r;
        float4 v = make_float4(0.f, 0.f, 0.f, 0.f);
        if (row < N_NODES) {
            v = *(const float4*)(X2 + (size_t)row * FHID + c4 * 4);
            float s = nsrc[row];
            v.x *= s; v.y *= s; v.z *= s; v.w *= s;
        }
        *(float4*)&Xs[r][c4 * 4] = v;
    }
    __syncthreads();
    const int r0 = t / FOUT;
    const int c = t % FOUT;
    float acc[4] = {0.f, 0.f, 0.f, 0.f};
    for (int k = 0; k < FHID; k++) {
        float b = Ws[k][c];
#pragma unroll
        for (int i = 0; i < 4; i++)
            acc[i] = fmaf(Xs[r0 + i * 8][k], b, acc[i]);
    }
#pragma unroll
    for (int i = 0; i < 4; i++) {
        int row = bm + r0 + i * 8;
        if (row < N_NODES) H2[(size_t)row * FOUT + c] = acc[i];
    }
}

// ---------------- SpMM2 gather + finish2: OUT = ndst * sum H2[src] + b2 ----------------
__global__ __launch_bounds__(256) void spmm2_gather(const int* __restrict__ rowptr,
                                                    const int* __restrict__ esrc,
                                                    const float* __restrict__ H2,
                                                    const float* __restrict__ ndst,
                                                    const float* __restrict__ b2,
                                                    float* __restrict__ OUT) {
    int node = blockIdx.x * (blockDim.x >> 6) + (threadIdx.x >> 6);
    if (node >= N_NODES) return;
    int lane = threadIdx.x & 63;
    int beg = rowptr[node], end = rowptr[node + 1];
    float acc = 0.f;
    int p = beg;
    for (; p + 1 < end; p += 2) {
        int s0 = esrc[p], s1 = esrc[p + 1];
        if (lane < FOUT) {
            float v0 = H2[(size_t)s0 * FOUT + lane];
            float v1 = H2[(size_t)s1 * FOUT + lane];
            acc += v0 + v1;
        }
    }
    if (p < end) {
        int s0 = esrc[p];
        if (lane < FOUT) acc += H2[(size_t)s0 * FOUT + lane];
    }
    if (lane < FOUT) {
        float nd = ndst[node];
        OUT[(size_t)node * FOUT + lane] = fmaf(acc, nd, b2[lane]);
    }
}

extern "C" void kernel_launch(void* const* d_in, const int* in_sizes, int n_in,
                              void* d_out, int out_size, void* d_ws, size_t ws_size,
                              hipStream_t stream) {
    const float* feat = (const float*)d_in[0];
    const int*   src  = (const int*)d_in[1];
    const int*   dst  = (const int*)d_in[2];
    const float* W1   = (const float*)d_in[3];
    const float* b1   = (const float*)d_in[4];
    const float* W2   = (const float*)d_in[5];
    const float* b2   = (const float*)d_in[6];
    float* out = (float*)d_out;

    char* ws = (char*)d_ws;
    const size_t SZ_BIG = (size_t)N_NODES * FHID * sizeof(float);   // 51.2 MB
    // bufA: H (bf16, 25.6MB) then H2 (fp32, 51.2MB)
    // bufB: deg/CSR scratch (12.8MB, dead after scatter2) then X2 (fp32, 51.2MB)
    unsigned short* Hbf = (unsigned short*)ws;
    float* bufA = (float*)ws;
    float* bufB = (float*)(ws + SZ_BIG);
    unsigned* scratch = (unsigned*)(ws + SZ_BIG);   // 2*8*16*12500*4 = 12.8MB
    char* small = ws + 2 * SZ_BIG;
    const size_t SSTRIDE = 401408;                  // 512B-aligned
    float*    nsrc   = (float*)(small);
    float*    ndst   = (float*)(small + SSTRIDE);
    unsigned* degI   = (unsigned*)(small + 2 * SSTRIDE);
    int*      rowptr = (int*)(small + 3 * SSTRIDE);
    unsigned* bsum   = (unsigned*)(small + 4 * SSTRIDE);
    unsigned short* Wt = (unsigned short*)(small + 5 * SSTRIDE);   // 128KB bf16 W1^T
    int*      esrc   = (int*)(small + 6 * SSTRIDE);                // 6.4 MB

    // CSR build (no global atomics, no memset needed)
    deg_hist<<<2 * NRANGE * GH, 256, 0, stream>>>(src, dst, scratch);
    deg_reduce<<<(N_NODES + 255) / 256, 256, 0, stream>>>(scratch, nsrc, ndst, degI);
    scan_blocksum<<<SCAN_NB, 256, 0, stream>>>(degI, bsum);
    scan_bsum<<<1, 128, 0, stream>>>(bsum, rowptr);
    scan_write<<<SCAN_NB, 256, 0, stream>>>(degI, bsum, rowptr);
    mkbase<<<(N_NODES + 255) / 256, 256, 0, stream>>>(scratch, rowptr);
    scatter2<<<NRANGE * GH, 256, 0, stream>>>(src, dst, scratch, esrc);
    wcvt_kernel<<<(FIN * FHID + 255) / 256, 256, 0, stream>>>(W1, Wt);

    gemm1_mfma<<<(N_NODES + 63) / 64, 256, 0, stream>>>(feat, Wt, nsrc, Hbf);                  // H -> bufA (bf16)
    spmm1_gather<<<(N_NODES + 3) / 4, 256, 0, stream>>>(rowptr, esrc, (const unsigned*)Hbf,
                                                        ndst, b1, bufB);                        // X2 -> bufB
    gemm2_kernel<<<(N_NODES + 31) / 32, 320, 0, stream>>>(bufB, W2, nsrc, bufA);               // H2 -> bufA
    spmm2_gather<<<(N_NODES + 3) / 4, 256, 0, stream>>>(rowptr, esrc, bufA, ndst, b2, out);
}

// Round 5
// 401.045 us; speedup vs baseline: 4.9212x; 1.0716x over previous
//
#include <hip/hip_runtime.h>

#define N_NODES 100000
#define N_EDGES 1600000
#define FIN 512
#define FHID 128
#define FOUT 40
#define FOUTP 48                // FOUT padded to 3x16 for MFMA

#define SCAN_CHUNK 1024
#define SCAN_NB ((N_NODES + SCAN_CHUNK - 1) / SCAN_CHUNK)   // 98

// CSR-build histogram geometry
#define NRANGE 8
#define RANGE_SZ 12500          // 8 * 12500 = 100000; 50KB LDS u32
#define GH 16                   // edge slices per task
#define EDGE_SLICE (N_EDGES / GH)   // 100000

typedef __attribute__((ext_vector_type(8))) short short8;   // 8 bf16 (4 VGPR)
typedef __attribute__((ext_vector_type(4))) float f32x4;    // MFMA acc

static __device__ inline unsigned short f2bf(float f) {
    unsigned x = __float_as_uint(f);
    unsigned r = (x + 0x7fffu + ((x >> 16) & 1u)) >> 16;    // RNE
    return (unsigned short)r;
}

// ---------------- deg_hist: LDS-privatized degree histograms, no global atomics ----
__global__ __launch_bounds__(256) void deg_hist(const int* __restrict__ src,
                                                const int* __restrict__ dst,
                                                unsigned* __restrict__ scratch) {
    __shared__ unsigned hist[RANGE_SZ];
    const int task = blockIdx.x / GH;
    const int g = blockIdx.x % GH;
    const int a = task / NRANGE;
    const int rg = task % NRANGE;
    const int lo = rg * RANGE_SZ;
    const int t = threadIdx.x;
    for (int i = t; i < RANGE_SZ; i += 256) hist[i] = 0;
    __syncthreads();
    const int* arr = a ? dst : src;
    const int4* p = (const int4*)(arr + g * EDGE_SLICE);
    for (int i = t; i < EDGE_SLICE / 4; i += 256) {
        int4 v = p[i];
        int x;
        x = v.x - lo; if ((unsigned)x < RANGE_SZ) atomicAdd(&hist[x], 1u);
        x = v.y - lo; if ((unsigned)x < RANGE_SZ) atomicAdd(&hist[x], 1u);
        x = v.z - lo; if ((unsigned)x < RANGE_SZ) atomicAdd(&hist[x], 1u);
        x = v.w - lo; if ((unsigned)x < RANGE_SZ) atomicAdd(&hist[x], 1u);
    }
    __syncthreads();
    unsigned* out = scratch + ((size_t)task * GH + g) * RANGE_SZ;
    for (int i = t; i < RANGE_SZ; i += 256) out[i] = hist[i];
}

// ---------------- deg_reduce: sum slices -> degI; fused norms ----------------
__global__ __launch_bounds__(256) void deg_reduce(const unsigned* __restrict__ scratch,
                                                  float* __restrict__ nsrc,
                                                  float* __restrict__ ndst,
                                                  unsigned* __restrict__ degI) {
    int i = blockIdx.x * 256 + threadIdx.x;
    if (i >= N_NODES) return;
    const int rg = i / RANGE_SZ;
    const int off = i % RANGE_SZ;
    const unsigned* ps = scratch + ((size_t)rg * GH) * RANGE_SZ + off;
    const unsigned* pd = scratch + ((size_t)(NRANGE + rg) * GH) * RANGE_SZ + off;
    unsigned so = 0, si = 0;
#pragma unroll
    for (int g = 0; g < GH; g++) {
        so += ps[(size_t)g * RANGE_SZ];
        si += pd[(size_t)g * RANGE_SZ];
    }
    degI[i] = si;
    nsrc[i] = rsqrtf((float)(so < 1u ? 1u : so));
    ndst[i] = rsqrtf((float)(si < 1u ? 1u : si));
}

// ---------------- CSR rowptr: exclusive scan of degI ----------------
__global__ __launch_bounds__(256) void scan_blocksum(const unsigned* __restrict__ deg,
                                                     unsigned* __restrict__ bsum) {
    __shared__ unsigned s[256];
    int b = blockIdx.x, t = threadIdx.x;
    int base = b * SCAN_CHUNK + t * 4;
    unsigned v = 0;
#pragma unroll
    for (int i = 0; i < 4; i++) { int idx = base + i; if (idx < N_NODES) v += deg[idx]; }
    s[t] = v; __syncthreads();
    for (int off = 128; off > 0; off >>= 1) {
        if (t < off) s[t] += s[t + off];
        __syncthreads();
    }
    if (t == 0) bsum[b] = s[0];
}

__global__ void scan_bsum(unsigned* __restrict__ bsum, int* __restrict__ rowptr) {
    __shared__ unsigned s[128];
    int t = threadIdx.x;
    if (t < SCAN_NB) s[t] = bsum[t];
    __syncthreads();
    if (t == 0) {
        unsigned run = 0;
        for (int i = 0; i < SCAN_NB; i++) { unsigned x = s[i]; s[i] = run; run += x; }
    }
    __syncthreads();
    if (t < SCAN_NB) bsum[t] = s[t];
    if (t == 0) rowptr[N_NODES] = N_EDGES;
}

__global__ __launch_bounds__(256) void scan_write(const unsigned* __restrict__ deg,
                                                  const unsigned* __restrict__ bsum,
                                                  int* __restrict__ rowptr) {
    __shared__ unsigned ts[256];
    int b = blockIdx.x, t = threadIdx.x;
    int base = b * SCAN_CHUNK + t * 4;
    unsigned v[4]; unsigned sum = 0;
#pragma unroll
    for (int i = 0; i < 4; i++) { int idx = base + i; v[i] = (idx < N_NODES) ? deg[idx] : 0u; sum += v[i]; }
    ts[t] = sum; __syncthreads();
    for (int off = 1; off < 256; off <<= 1) {
        unsigned add = (t >= off) ? ts[t - off] : 0u;
        __syncthreads();
        ts[t] += add;
        __syncthreads();
    }
    unsigned excl = (t == 0) ? 0u : ts[t - 1];
    unsigned run = bsum[b] + excl;
#pragma unroll
    for (int i = 0; i < 4; i++) {
        int idx = base + i;
        if (idx < N_NODES) rowptr[idx] = (int)run;
        run += v[i];
    }
}

// ---------------- mkbase: dst-half scratch counts -> per-(slice,node) CSR bases ----
__global__ __launch_bounds__(256) void mkbase(unsigned* __restrict__ scratch,
                                              const int* __restrict__ rowptr) {
    int i = blockIdx.x * 256 + threadIdx.x;
    if (i >= N_NODES) return;
    const int rg = i / RANGE_SZ;
    const int off = i % RANGE_SZ;
    unsigned* pd = scratch + ((size_t)(NRANGE + rg) * GH) * RANGE_SZ + off;
    unsigned run = (unsigned)rowptr[i];
#pragma unroll
    for (int g = 0; g < GH; g++) {
        unsigned c = pd[(size_t)g * RANGE_SZ];
        pd[(size_t)g * RANGE_SZ] = run;
        run += c;
    }
}

// ---------------- scatter2: CSR slot assignment via LDS cursors only ----------------
__global__ __launch_bounds__(256) void scatter2(const int* __restrict__ src,
                                                const int* __restrict__ dst,
                                                const unsigned* __restrict__ scratch,
                                                int* __restrict__ esrc) {
    __shared__ unsigned cur[RANGE_SZ];
    const int rg = blockIdx.x / GH;
    const int g = blockIdx.x % GH;
    const int lo = rg * RANGE_SZ;
    const int t = threadIdx.x;
    const unsigned* base = scratch + ((size_t)(NRANGE + rg) * GH + g) * RANGE_SZ;
    for (int i = t; i < RANGE_SZ; i += 256) cur[i] = base[i];
    __syncthreads();
    const int4* pd = (const int4*)(dst + g * EDGE_SLICE);
    const int4* ps = (const int4*)(src + g * EDGE_SLICE);
    for (int i = t; i < EDGE_SLICE / 4; i += 256) {
        int4 d4 = pd[i];
        int4 s4 = ps[i];
        int x;
        x = d4.x - lo; if ((unsigned)x < RANGE_SZ) esrc[atomicAdd(&cur[x], 1u)] = s4.x;
        x = d4.y - lo; if ((unsigned)x < RANGE_SZ) esrc[atomicAdd(&cur[x], 1u)] = s4.y;
        x = d4.z - lo; if ((unsigned)x < RANGE_SZ) esrc[atomicAdd(&cur[x], 1u)] = s4.z;
        x = d4.w - lo; if ((unsigned)x < RANGE_SZ) esrc[atomicAdd(&cur[x], 1u)] = s4.w;
    }
}

// ---------------- W1 -> bf16 transposed: Wt[n][k] = bf16(W1[k][n]) ----------------
__global__ __launch_bounds__(256) void wcvt_kernel(const float* __restrict__ W1,
                                                   unsigned short* __restrict__ Wt) {
    int j = blockIdx.x * blockDim.x + threadIdx.x;   // j = k*128 + n
    if (j < FIN * FHID) {
        int k = j >> 7;
        int n = j & 127;
        Wt[n * FIN + k] = f2bf(W1[j]);
    }
}

// ---------------- W2 -> bf16 transposed padded: W2t[n][k], n in [0,48) ----------------
__global__ __launch_bounds__(256) void w2cvt_kernel(const float* __restrict__ W2,
                                                    unsigned short* __restrict__ W2t) {
    int j = blockIdx.x * blockDim.x + threadIdx.x;   // j = n*128 + k
    if (j < FOUTP * FHID) {
        int n = j >> 7;
        int k = j & 127;
        W2t[j] = (n < FOUT) ? f2bf(W2[k * FOUT + n]) : (unsigned short)0;
    }
}

// ---------------- GEMM1 (bf16 MFMA): H = bf16(X*nsrc) @ bf16(W1), H stored bf16 ----
__global__ __launch_bounds__(256) void gemm1_mfma(const float* __restrict__ X,
                                                  const unsigned short* __restrict__ Wt,
                                                  const float* __restrict__ nsrc,
                                                  unsigned short* __restrict__ H) {
    __shared__ __align__(16) unsigned short Xs[64 * 64];    // 8KB  [row][k]
    __shared__ __align__(16) unsigned short Bs[128 * 64];   // 16KB [col][k]
    const int t = threadIdx.x;
    const int bm = blockIdx.x * 64;
    const int w = t >> 6;
    const int l = t & 63;
    const int r = l & 15;
    const int kg = l >> 4;

    f32x4 acc[8];
#pragma unroll
    for (int c = 0; c < 8; c++) acc[c] = (f32x4){0.f, 0.f, 0.f, 0.f};

    for (int s = 0; s < FIN / 64; ++s) {
        const int k0 = s * 64;
#pragma unroll
        for (int i = 0; i < 2; i++) {
            int idx = t + i * 256;
            int row = idx >> 3;
            int slot = idx & 7;
            int grow = bm + row;
            unsigned short u[8];
            if (grow < N_NODES) {
                const float* p = X + (size_t)grow * FIN + k0 + slot * 8;
                float4 v0 = *(const float4*)(p);
                float4 v1 = *(const float4*)(p + 4);
                float sc = nsrc[grow];
                u[0] = f2bf(v0.x * sc); u[1] = f2bf(v0.y * sc);
                u[2] = f2bf(v0.z * sc); u[3] = f2bf(v0.w * sc);
                u[4] = f2bf(v1.x * sc); u[5] = f2bf(v1.y * sc);
                u[6] = f2bf(v1.z * sc); u[7] = f2bf(v1.w * sc);
            } else {
#pragma unroll
                for (int q = 0; q < 8; q++) u[q] = 0;
            }
            uint4 packed;
            packed.x = (unsigned)u[0] | ((unsigned)u[1] << 16);
            packed.y = (unsigned)u[2] | ((unsigned)u[3] << 16);
            packed.z = (unsigned)u[4] | ((unsigned)u[5] << 16);
            packed.w = (unsigned)u[6] | ((unsigned)u[7] << 16);
            *(uint4*)&Xs[row * 64 + ((slot ^ (row & 7)) * 8)] = packed;
        }
#pragma unroll
        for (int i = 0; i < 4; i++) {
            int idx = t + i * 256;
            int col = idx >> 3;
            int slot = idx & 7;
            uint4 packed = *(const uint4*)&Wt[col * FIN + k0 + slot * 8];
            *(uint4*)&Bs[col * 64 + ((slot ^ (col & 7)) * 8)] = packed;
        }
        __syncthreads();
        const int arow = w * 16 + r;
        short8 a0 = *(const short8*)&Xs[arow * 64 + (((0 + kg) ^ (r & 7)) * 8)];
        short8 a1 = *(const short8*)&Xs[arow * 64 + (((4 + kg) ^ (r & 7)) * 8)];
#pragma unroll
        for (int c = 0; c < 8; c++) {
            const int brow = c * 16 + r;
            short8 b0 = *(const short8*)&Bs[brow * 64 + (((0 + kg) ^ (r & 7)) * 8)];
            short8 b1 = *(const short8*)&Bs[brow * 64 + (((4 + kg) ^ (r & 7)) * 8)];
            acc[c] = __builtin_amdgcn_mfma_f32_16x16x32_bf16(a0, b0, acc[c], 0, 0, 0);
            acc[c] = __builtin_amdgcn_mfma_f32_16x16x32_bf16(a1, b1, acc[c], 0, 0, 0);
        }
        __syncthreads();
    }
#pragma unroll
    for (int j = 0; j < 4; j++) {
        int grow = bm + w * 16 + kg * 4 + j;
        if (grow < N_NODES) {
#pragma unroll
            for (int c = 0; c < 8; c++)
                H[(size_t)grow * FHID + c * 16 + r] = f2bf(acc[c][j]);
        }
    }
}

// ---------------- SpMM1 gather (bf16 H) + finish1: X2 = relu(ndst*sum H[src] + b1), bf16 out ----
__global__ __launch_bounds__(256) void spmm1_gather(const int* __restrict__ rowptr,
                                                    const int* __restrict__ esrc,
                                                    const unsigned* __restrict__ H,   // bf16x2
                                                    const float* __restrict__ ndst,
                                                    const float* __restrict__ b1,
                                                    unsigned* __restrict__ X2) {      // bf16x2
    int node = blockIdx.x * (blockDim.x >> 6) + (threadIdx.x >> 6);
    if (node >= N_NODES) return;
    int lane = threadIdx.x & 63;
    int beg = rowptr[node], end = rowptr[node + 1];
    float2 acc = make_float2(0.f, 0.f);
    int p = beg;
    for (; p + 1 < end; p += 2) {
        int s0 = esrc[p], s1 = esrc[p + 1];
        unsigned u0 = H[(size_t)s0 * (FHID / 2) + lane];
        unsigned u1 = H[(size_t)s1 * (FHID / 2) + lane];
        acc.x += __uint_as_float(u0 << 16) + __uint_as_float(u1 << 16);
        acc.y += __uint_as_float(u0 & 0xffff0000u) + __uint_as_float(u1 & 0xffff0000u);
    }
    if (p < end) {
        int s0 = esrc[p];
        unsigned u0 = H[(size_t)s0 * (FHID / 2) + lane];
        acc.x += __uint_as_float(u0 << 16);
        acc.y += __uint_as_float(u0 & 0xffff0000u);
    }
    float nd = ndst[node];
    float2 b = *(const float2*)(b1 + lane * 2);
    float ox = fmaxf(fmaf(acc.x, nd, b.x), 0.f);
    float oy = fmaxf(fmaf(acc.y, nd, b.y), 0.f);
    X2[(size_t)node * (FHID / 2) + lane] = (unsigned)f2bf(ox) | ((unsigned)f2bf(oy) << 16);
}

// ---------------- GEMM2 (bf16 MFMA, single-shot K=128): H2 = bf16(X2*?) ... wait,
// nsrc must scale X2 before matmul: H2 = (X2*nsrc) @ W2, H2 stored bf16 [N][40].
// Tile: 64 rows x 48 cols, 4 waves (16 rows each), 3 col-tiles, K=128 in one LDS stage.
// Swizzle: 16B slot index (0..15) ^= (row & 15); 2-way bank aliasing = free.
__global__ __launch_bounds__(256) void gemm2_mfma(const unsigned* __restrict__ X2,   // bf16x2
                                                  const unsigned short* __restrict__ W2t,
                                                  const float* __restrict__ nsrc,
                                                  unsigned short* __restrict__ H2) {
    __shared__ __align__(16) unsigned short Xs[64 * 128];    // 16KB
    __shared__ __align__(16) unsigned short Bs[FOUTP * 128]; // 12KB
    const int t = threadIdx.x;
    const int bm = blockIdx.x * 64;
    const int w = t >> 6;
    const int l = t & 63;
    const int r = l & 15;
    const int kg = l >> 4;

    // stage X2 tile: 64 rows x 16 slots = 1024 uint4 tasks, 4/thread; scale by nsrc
#pragma unroll
    for (int i = 0; i < 4; i++) {
        int idx = t + i * 256;
        int row = idx >> 4;
        int slot = idx & 15;
        int grow = bm + row;
        uint4 packed = make_uint4(0u, 0u, 0u, 0u);
        if (grow < N_NODES) {
            uint4 v = ((const uint4*)X2)[(size_t)grow * 16 + slot];
            float sc = nsrc[grow];
            unsigned short u[8];
            u[0] = f2bf(__uint_as_float(v.x << 16) * sc);
            u[1] = f2bf(__uint_as_float(v.x & 0xffff0000u) * sc);
            u[2] = f2bf(__uint_as_float(v.y << 16) * sc);
            u[3] = f2bf(__uint_as_float(v.y & 0xffff0000u) * sc);
            u[4] = f2bf(__uint_as_float(v.z << 16) * sc);
            u[5] = f2bf(__uint_as_float(v.z & 0xffff0000u) * sc);
            u[6] = f2bf(__uint_as_float(v.w << 16) * sc);
            u[7] = f2bf(__uint_as_float(v.w & 0xffff0000u) * sc);
            packed.x = (unsigned)u[0] | ((unsigned)u[1] << 16);
            packed.y = (unsigned)u[2] | ((unsigned)u[3] << 16);
            packed.z = (unsigned)u[4] | ((unsigned)u[5] << 16);
            packed.w = (unsigned)u[6] | ((unsigned)u[7] << 16);
        }
        *(uint4*)&Xs[row * 128 + ((slot ^ (row & 15)) * 8)] = packed;
    }
    // stage W2t: 48 rows x 16 slots = 768 uint4 tasks, 3/thread
#pragma unroll
    for (int i = 0; i < 3; i++) {
        int idx = t + i * 256;
        int row = idx >> 4;
        int slot = idx & 15;
        uint4 packed = *(const uint4*)&W2t[row * 128 + slot * 8];
        *(uint4*)&Bs[row * 128 + ((slot ^ (row & 15)) * 8)] = packed;
    }
    __syncthreads();

    f32x4 acc[3];
#pragma unroll
    for (int c = 0; c < 3; c++) acc[c] = (f32x4){0.f, 0.f, 0.f, 0.f};
    const int arow = w * 16 + r;
#pragma unroll
    for (int ks = 0; ks < 4; ks++) {
        short8 a = *(const short8*)&Xs[arow * 128 + (((ks * 4 + kg) ^ r) * 8)];
#pragma unroll
        for (int c = 0; c < 3; c++) {
            const int brow = c * 16 + r;
            short8 b = *(const short8*)&Bs[brow * 128 + (((ks * 4 + kg) ^ r) * 8)];
            acc[c] = __builtin_amdgcn_mfma_f32_16x16x32_bf16(a, b, acc[c], 0, 0, 0);
        }
    }
    // epilogue: col = c*16 + r (keep col < 40), row = w*16 + kg*4 + j
#pragma unroll
    for (int j = 0; j < 4; j++) {
        int grow = bm + w * 16 + kg * 4 + j;
        if (grow < N_NODES) {
#pragma unroll
            for (int c = 0; c < 3; c++) {
                int col = c * 16 + r;
                if (col < FOUT)
                    H2[(size_t)grow * FOUT + col] = f2bf(acc[c][j]);
            }
        }
    }
}

// ---------------- SpMM2 gather (bf16 H2) + finish2: OUT = ndst * sum H2[src] + b2 ----
__global__ __launch_bounds__(256) void spmm2_gather(const int* __restrict__ rowptr,
                                                    const int* __restrict__ esrc,
                                                    const unsigned* __restrict__ H2,  // bf16x2, 20 u32/row
                                                    const float* __restrict__ ndst,
                                                    const float* __restrict__ b2,
                                                    float* __restrict__ OUT) {
    int node = blockIdx.x * (blockDim.x >> 6) + (threadIdx.x >> 6);
    if (node >= N_NODES) return;
    int lane = threadIdx.x & 63;
    int beg = rowptr[node], end = rowptr[node + 1];
    float2 acc = make_float2(0.f, 0.f);
    int p = beg;
    for (; p + 1 < end; p += 2) {
        int s0 = esrc[p], s1 = esrc[p + 1];
        if (lane < FOUT / 2) {
            unsigned u0 = H2[(size_t)s0 * (FOUT / 2) + lane];
            unsigned u1 = H2[(size_t)s1 * (FOUT / 2) + lane];
            acc.x += __uint_as_float(u0 << 16) + __uint_as_float(u1 << 16);
            acc.y += __uint_as_float(u0 & 0xffff0000u) + __uint_as_float(u1 & 0xffff0000u);
        }
    }
    if (p < end) {
        int s0 = esrc[p];
        if (lane < FOUT / 2) {
            unsigned u0 = H2[(size_t)s0 * (FOUT / 2) + lane];
            acc.x += __uint_as_float(u0 << 16);
            acc.y += __uint_as_float(u0 & 0xffff0000u);
        }
    }
    if (lane < FOUT / 2) {
        float nd = ndst[node];
        float2 b = *(const float2*)(b2 + lane * 2);
        float2 o;
        o.x = fmaf(acc.x, nd, b.x);
        o.y = fmaf(acc.y, nd, b.y);
        *(float2*)(OUT + (size_t)node * FOUT + lane * 2) = o;
    }
}

extern "C" void kernel_launch(void* const* d_in, const int* in_sizes, int n_in,
                              void* d_out, int out_size, void* d_ws, size_t ws_size,
                              hipStream_t stream) {
    const float* feat = (const float*)d_in[0];
    const int*   src  = (const int*)d_in[1];
    const int*   dst  = (const int*)d_in[2];
    const float* W1   = (const float*)d_in[3];
    const float* b1   = (const float*)d_in[4];
    const float* W2   = (const float*)d_in[5];
    const float* b2   = (const float*)d_in[6];
    float* out = (float*)d_out;

    char* ws = (char*)d_ws;
    const size_t SZ_BIG = (size_t)N_NODES * FHID * sizeof(float);   // 51.2 MB
    // Layout:
    //  [0, 25.6MB)          Hbf   (bf16 H, gemm1 out)
    //  [SZ_BIG, +12.8MB)    scratch (deg/CSR; dead after scatter2)
    //  [SZ_BIG, +25.6MB)    X2bf  (bf16 X2, spmm1 out; reuses scratch space)
    //  [SZ_BIG+32MB, +8MB)  H2bf  (bf16 H2, gemm2 out)
    unsigned short* Hbf  = (unsigned short*)ws;
    unsigned*       X2u  = (unsigned*)(ws + SZ_BIG);
    unsigned*       scratch = (unsigned*)(ws + SZ_BIG);
    unsigned short* H2bf = (unsigned short*)(ws + SZ_BIG + (32u << 20));
    char* small = ws + 2 * SZ_BIG;
    const size_t SSTRIDE = 401408;                  // 512B-aligned
    float*    nsrc   = (float*)(small);
    float*    ndst   = (float*)(small + SSTRIDE);
    unsigned* degI   = (unsigned*)(small + 2 * SSTRIDE);
    int*      rowptr = (int*)(small + 3 * SSTRIDE);
    unsigned* bsum   = (unsigned*)(small + 4 * SSTRIDE);
    unsigned short* Wt  = (unsigned short*)(small + 5 * SSTRIDE);            // 128KB bf16 W1^T
    unsigned short* W2t = (unsigned short*)(small + 5 * SSTRIDE + 131072);   // 12KB bf16 W2^T padded
    int*      esrc   = (int*)(small + 6 * SSTRIDE);                          // 6.4 MB

    // CSR build (no global atomics, no memset needed)
    deg_hist<<<2 * NRANGE * GH, 256, 0, stream>>>(src, dst, scratch);
    deg_reduce<<<(N_NODES + 255) / 256, 256, 0, stream>>>(scratch, nsrc, ndst, degI);
    scan_blocksum<<<SCAN_NB, 256, 0, stream>>>(degI, bsum);
    scan_bsum<<<1, 128, 0, stream>>>(bsum, rowptr);
    scan_write<<<SCAN_NB, 256, 0, stream>>>(degI, bsum, rowptr);
    mkbase<<<(N_NODES + 255) / 256, 256, 0, stream>>>(scratch, rowptr);
    scatter2<<<NRANGE * GH, 256, 0, stream>>>(src, dst, scratch, esrc);
    wcvt_kernel<<<(FIN * FHID + 255) / 256, 256, 0, stream>>>(W1, Wt);
    w2cvt_kernel<<<(FOUTP * FHID + 255) / 256, 256, 0, stream>>>(W2, W2t);

    gemm1_mfma<<<(N_NODES + 63) / 64, 256, 0, stream>>>(feat, Wt, nsrc, Hbf);
    spmm1_gather<<<(N_NODES + 3) / 4, 256, 0, stream>>>(rowptr, esrc, (const unsigned*)Hbf,
                                                        ndst, b1, X2u);          // X2 (bf16) — scratch now dead
    gemm2_mfma<<<(N_NODES + 63) / 64, 256, 0, stream>>>(X2u, W2t, nsrc, H2bf);
    spmm2_gather<<<(N_NODES + 3) / 4, 256, 0, stream>>>(rowptr, esrc, (const unsigned*)H2bf,
                                                        ndst, b2, out);
}

// Round 6
// 317.163 us; speedup vs baseline: 6.2227x; 1.2645x over previous
//
#include <hip/hip_runtime.h>
#include <hip/hip_bf16.h>

#define N_NODES 100000
#define N_EDGES 1600000
#define FIN 512
#define FHID 128
#define FOUT 40
#define FOUTP 48                // FOUT padded to 3x16 for MFMA

#define SCAN_CHUNK 1024
#define SCAN_NB ((N_NODES + SCAN_CHUNK - 1) / SCAN_CHUNK)   // 98

// CSR-build histogram geometry
#define NRANGE 8
#define RANGE_SZ 12500          // 8 * 12500 = 100000; 50KB LDS u32
#define GH 16                   // edge slices per task
#define EDGE_SLICE (N_EDGES / GH)   // 100000

typedef __attribute__((ext_vector_type(8))) short short8;   // 8 bf16 (4 VGPR)
typedef __attribute__((ext_vector_type(4))) float f32x4;    // MFMA acc

static __device__ inline unsigned short f2bf(float f) {     // cold paths only
    unsigned x = __float_as_uint(f);
    unsigned r = (x + 0x7fffu + ((x >> 16) & 1u)) >> 16;    // RNE
    return (unsigned short)r;
}

// hot-path pair conversion -> v_cvt_pk_bf16_f32 (compiler-emitted)
static __device__ inline unsigned pk2bf(float lo, float hi) {
    __hip_bfloat162 h = __float22bfloat162_rn(make_float2(lo, hi));
    return *(unsigned*)&h;
}
static __device__ inline unsigned short bf1(float f) {
    __hip_bfloat16 h = __float2bfloat16(f);
    return *(unsigned short*)&h;
}

// ---------------- deg_hist: LDS-privatized degree histograms, no global atomics ----
__global__ __launch_bounds__(256) void deg_hist(const int* __restrict__ src,
                                                const int* __restrict__ dst,
                                                unsigned* __restrict__ scratch) {
    __shared__ unsigned hist[RANGE_SZ];
    const int task = blockIdx.x / GH;
    const int g = blockIdx.x % GH;
    const int a = task / NRANGE;
    const int rg = task % NRANGE;
    const int lo = rg * RANGE_SZ;
    const int t = threadIdx.x;
    for (int i = t; i < RANGE_SZ; i += 256) hist[i] = 0;
    __syncthreads();
    const int* arr = a ? dst : src;
    const int4* p = (const int4*)(arr + g * EDGE_SLICE);
    for (int i = t; i < EDGE_SLICE / 4; i += 256) {
        int4 v = p[i];
        int x;
        x = v.x - lo; if ((unsigned)x < RANGE_SZ) atomicAdd(&hist[x], 1u);
        x = v.y - lo; if ((unsigned)x < RANGE_SZ) atomicAdd(&hist[x], 1u);
        x = v.z - lo; if ((unsigned)x < RANGE_SZ) atomicAdd(&hist[x], 1u);
        x = v.w - lo; if ((unsigned)x < RANGE_SZ) atomicAdd(&hist[x], 1u);
    }
    __syncthreads();
    unsigned* out = scratch + ((size_t)task * GH + g) * RANGE_SZ;
    for (int i = t; i < RANGE_SZ; i += 256) out[i] = hist[i];
}

// ---------------- deg_reduce: sum slices -> degI; fused norms ----------------
__global__ __launch_bounds__(256) void deg_reduce(const unsigned* __restrict__ scratch,
                                                  float* __restrict__ nsrc,
                                                  float* __restrict__ ndst,
                                                  unsigned* __restrict__ degI) {
    int i = blockIdx.x * 256 + threadIdx.x;
    if (i >= N_NODES) return;
    const int rg = i / RANGE_SZ;
    const int off = i % RANGE_SZ;
    const unsigned* ps = scratch + ((size_t)rg * GH) * RANGE_SZ + off;
    const unsigned* pd = scratch + ((size_t)(NRANGE + rg) * GH) * RANGE_SZ + off;
    unsigned so = 0, si = 0;
#pragma unroll
    for (int g = 0; g < GH; g++) {
        so += ps[(size_t)g * RANGE_SZ];
        si += pd[(size_t)g * RANGE_SZ];
    }
    degI[i] = si;
    nsrc[i] = rsqrtf((float)(so < 1u ? 1u : so));
    ndst[i] = rsqrtf((float)(si < 1u ? 1u : si));
}

// ---------------- CSR rowptr: exclusive scan of degI ----------------
__global__ __launch_bounds__(256) void scan_blocksum(const unsigned* __restrict__ deg,
                                                     unsigned* __restrict__ bsum) {
    __shared__ unsigned s[256];
    int b = blockIdx.x, t = threadIdx.x;
    int base = b * SCAN_CHUNK + t * 4;
    unsigned v = 0;
#pragma unroll
    for (int i = 0; i < 4; i++) { int idx = base + i; if (idx < N_NODES) v += deg[idx]; }
    s[t] = v; __syncthreads();
    for (int off = 128; off > 0; off >>= 1) {
        if (t < off) s[t] += s[t + off];
        __syncthreads();
    }
    if (t == 0) bsum[b] = s[0];
}

__global__ void scan_bsum(unsigned* __restrict__ bsum, int* __restrict__ rowptr) {
    __shared__ unsigned s[128];
    int t = threadIdx.x;
    if (t < SCAN_NB) s[t] = bsum[t];
    __syncthreads();
    if (t == 0) {
        unsigned run = 0;
        for (int i = 0; i < SCAN_NB; i++) { unsigned x = s[i]; s[i] = run; run += x; }
    }
    __syncthreads();
    if (t < SCAN_NB) bsum[t] = s[t];
    if (t == 0) rowptr[N_NODES] = N_EDGES;
}

__global__ __launch_bounds__(256) void scan_write(const unsigned* __restrict__ deg,
                                                  const unsigned* __restrict__ bsum,
                                                  int* __restrict__ rowptr) {
    __shared__ unsigned ts[256];
    int b = blockIdx.x, t = threadIdx.x;
    int base = b * SCAN_CHUNK + t * 4;
    unsigned v[4]; unsigned sum = 0;
#pragma unroll
    for (int i = 0; i < 4; i++) { int idx = base + i; v[i] = (idx < N_NODES) ? deg[idx] : 0u; sum += v[i]; }
    ts[t] = sum; __syncthreads();
    for (int off = 1; off < 256; off <<= 1) {
        unsigned add = (t >= off) ? ts[t - off] : 0u;
        __syncthreads();
        ts[t] += add;
        __syncthreads();
    }
    unsigned excl = (t == 0) ? 0u : ts[t - 1];
    unsigned run = bsum[b] + excl;
#pragma unroll
    for (int i = 0; i < 4; i++) {
        int idx = base + i;
        if (idx < N_NODES) rowptr[idx] = (int)run;
        run += v[i];
    }
}

// ---------------- mkbase: dst-half scratch counts -> per-(slice,node) CSR bases ----
__global__ __launch_bounds__(256) void mkbase(unsigned* __restrict__ scratch,
                                              const int* __restrict__ rowptr) {
    int i = blockIdx.x * 256 + threadIdx.x;
    if (i >= N_NODES) return;
    const int rg = i / RANGE_SZ;
    const int off = i % RANGE_SZ;
    unsigned* pd = scratch + ((size_t)(NRANGE + rg) * GH) * RANGE_SZ + off;
    unsigned run = (unsigned)rowptr[i];
#pragma unroll
    for (int g = 0; g < GH; g++) {
        unsigned c = pd[(size_t)g * RANGE_SZ];
        pd[(size_t)g * RANGE_SZ] = run;
        run += c;
    }
}

// ---------------- scatter2: CSR slot assignment via LDS cursors only ----------------
__global__ __launch_bounds__(256) void scatter2(const int* __restrict__ src,
                                                const int* __restrict__ dst,
                                                const unsigned* __restrict__ scratch,
                                                int* __restrict__ esrc) {
    __shared__ unsigned cur[RANGE_SZ];
    const int rg = blockIdx.x / GH;
    const int g = blockIdx.x % GH;
    const int lo = rg * RANGE_SZ;
    const int t = threadIdx.x;
    const unsigned* base = scratch + ((size_t)(NRANGE + rg) * GH + g) * RANGE_SZ;
    for (int i = t; i < RANGE_SZ; i += 256) cur[i] = base[i];
    __syncthreads();
    const int4* pd = (const int4*)(dst + g * EDGE_SLICE);
    const int4* ps = (const int4*)(src + g * EDGE_SLICE);
    for (int i = t; i < EDGE_SLICE / 4; i += 256) {
        int4 d4 = pd[i];
        int4 s4 = ps[i];
        int x;
        x = d4.x - lo; if ((unsigned)x < RANGE_SZ) esrc[atomicAdd(&cur[x], 1u)] = s4.x;
        x = d4.y - lo; if ((unsigned)x < RANGE_SZ) esrc[atomicAdd(&cur[x], 1u)] = s4.y;
        x = d4.z - lo; if ((unsigned)x < RANGE_SZ) esrc[atomicAdd(&cur[x], 1u)] = s4.z;
        x = d4.w - lo; if ((unsigned)x < RANGE_SZ) esrc[atomicAdd(&cur[x], 1u)] = s4.w;
    }
}

// ---------------- W1 -> bf16 transposed: Wt[n][k] = bf16(W1[k][n]) ----------------
__global__ __launch_bounds__(256) void wcvt_kernel(const float* __restrict__ W1,
                                                   unsigned short* __restrict__ Wt) {
    int j = blockIdx.x * blockDim.x + threadIdx.x;   // j = k*128 + n
    if (j < FIN * FHID) {
        int k = j >> 7;
        int n = j & 127;
        Wt[n * FIN + k] = f2bf(W1[j]);
    }
}

// ---------------- W2 -> bf16 transposed padded: W2t[n][k], n in [0,48) ----------------
__global__ __launch_bounds__(256) void w2cvt_kernel(const float* __restrict__ W2,
                                                    unsigned short* __restrict__ W2t) {
    int j = blockIdx.x * blockDim.x + threadIdx.x;   // j = n*128 + k
    if (j < FOUTP * FHID) {
        int n = j >> 7;
        int k = j & 127;
        W2t[j] = (n < FOUT) ? f2bf(W2[k * FOUT + n]) : (unsigned short)0;
    }
}

// ---------------- GEMM1 (bf16 MFMA): H = nsrc * (bf16(X) @ bf16(W1)), H stored bf16 ----
// nsrc factored to the fp32 epilogue (per-row scalar commutes with the matmul).
__global__ __launch_bounds__(256) void gemm1_mfma(const float* __restrict__ X,
                                                  const unsigned short* __restrict__ Wt,
                                                  const float* __restrict__ nsrc,
                                                  unsigned short* __restrict__ H) {
    __shared__ __align__(16) unsigned short Xs[64 * 64];    // 8KB  [row][k]
    __shared__ __align__(16) unsigned short Bs[128 * 64];   // 16KB [col][k]
    const int t = threadIdx.x;
    const int bm = blockIdx.x * 64;
    const int w = t >> 6;
    const int l = t & 63;
    const int r = l & 15;
    const int kg = l >> 4;

    f32x4 acc[8];
#pragma unroll
    for (int c = 0; c < 8; c++) acc[c] = (f32x4){0.f, 0.f, 0.f, 0.f};

    for (int s = 0; s < FIN / 64; ++s) {
        const int k0 = s * 64;
#pragma unroll
        for (int i = 0; i < 2; i++) {
            int idx = t + i * 256;
            int row = idx >> 3;
            int slot = idx & 7;
            int grow = bm + row;
            uint4 packed = make_uint4(0u, 0u, 0u, 0u);
            if (grow < N_NODES) {
                const float4* p = (const float4*)(X + (size_t)grow * FIN + k0 + slot * 8);
                float4 v0 = p[0];
                float4 v1 = p[1];
                packed.x = pk2bf(v0.x, v0.y);
                packed.y = pk2bf(v0.z, v0.w);
                packed.z = pk2bf(v1.x, v1.y);
                packed.w = pk2bf(v1.z, v1.w);
            }
            *(uint4*)&Xs[row * 64 + ((slot ^ (row & 7)) * 8)] = packed;
        }
#pragma unroll
        for (int i = 0; i < 4; i++) {
            int idx = t + i * 256;
            int col = idx >> 3;
            int slot = idx & 7;
            uint4 packed = *(const uint4*)&Wt[col * FIN + k0 + slot * 8];
            *(uint4*)&Bs[col * 64 + ((slot ^ (col & 7)) * 8)] = packed;
        }
        __syncthreads();
        const int arow = w * 16 + r;
        short8 a0 = *(const short8*)&Xs[arow * 64 + (((0 + kg) ^ (r & 7)) * 8)];
        short8 a1 = *(const short8*)&Xs[arow * 64 + (((4 + kg) ^ (r & 7)) * 8)];
#pragma unroll
        for (int c = 0; c < 8; c++) {
            const int brow = c * 16 + r;
            short8 b0 = *(const short8*)&Bs[brow * 64 + (((0 + kg) ^ (r & 7)) * 8)];
            short8 b1 = *(const short8*)&Bs[brow * 64 + (((4 + kg) ^ (r & 7)) * 8)];
            acc[c] = __builtin_amdgcn_mfma_f32_16x16x32_bf16(a0, b0, acc[c], 0, 0, 0);
            acc[c] = __builtin_amdgcn_mfma_f32_16x16x32_bf16(a1, b1, acc[c], 0, 0, 0);
        }
        __syncthreads();
    }
    // epilogue: scale by nsrc[row], store bf16. C/D: col=lane&15, row=(lane>>4)*4+reg
#pragma unroll
    for (int j = 0; j < 4; j++) {
        int grow = bm + w * 16 + kg * 4 + j;
        if (grow < N_NODES) {
            float sc = nsrc[grow];
#pragma unroll
            for (int c = 0; c < 8; c++)
                H[(size_t)grow * FHID + c * 16 + r] = bf1(acc[c][j] * sc);
        }
    }
}

// ---------------- SpMM1 gather (bf16 H) + finish1: X2 = relu(ndst*sum H[src] + b1), bf16 out ----
__global__ __launch_bounds__(256) void spmm1_gather(const int* __restrict__ rowptr,
                                                    const int* __restrict__ esrc,
                                                    const unsigned* __restrict__ H,   // bf16x2
                                                    const float* __restrict__ ndst,
                                                    const float* __restrict__ b1,
                                                    unsigned* __restrict__ X2) {      // bf16x2
    int node = blockIdx.x * (blockDim.x >> 6) + (threadIdx.x >> 6);
    if (node >= N_NODES) return;
    int lane = threadIdx.x & 63;
    int beg = rowptr[node], end = rowptr[node + 1];
    float2 acc0 = make_float2(0.f, 0.f);
    float2 acc1 = make_float2(0.f, 0.f);
    int p = beg;
    for (; p + 3 < end; p += 4) {
        int s0 = esrc[p], s1 = esrc[p + 1], s2 = esrc[p + 2], s3 = esrc[p + 3];
        unsigned u0 = H[(size_t)s0 * (FHID / 2) + lane];
        unsigned u1 = H[(size_t)s1 * (FHID / 2) + lane];
        unsigned u2 = H[(size_t)s2 * (FHID / 2) + lane];
        unsigned u3 = H[(size_t)s3 * (FHID / 2) + lane];
        acc0.x += __uint_as_float(u0 << 16) + __uint_as_float(u1 << 16);
        acc0.y += __uint_as_float(u0 & 0xffff0000u) + __uint_as_float(u1 & 0xffff0000u);
        acc1.x += __uint_as_float(u2 << 16) + __uint_as_float(u3 << 16);
        acc1.y += __uint_as_float(u2 & 0xffff0000u) + __uint_as_float(u3 & 0xffff0000u);
    }
    for (; p < end; ++p) {
        int s0 = esrc[p];
        unsigned u0 = H[(size_t)s0 * (FHID / 2) + lane];
        acc0.x += __uint_as_float(u0 << 16);
        acc0.y += __uint_as_float(u0 & 0xffff0000u);
    }
    acc0.x += acc1.x; acc0.y += acc1.y;
    float nd = ndst[node];
    float2 b = *(const float2*)(b1 + lane * 2);
    float ox = fmaxf(fmaf(acc0.x, nd, b.x), 0.f);
    float oy = fmaxf(fmaf(acc0.y, nd, b.y), 0.f);
    X2[(size_t)node * (FHID / 2) + lane] = pk2bf(ox, oy);
}

// ---------------- GEMM2 (bf16 MFMA, single-shot K=128): H2 = nsrc * (X2 @ W2), bf16 out ----
// X2 already bf16 -> staging is a pure swizzled copy; nsrc applied in epilogue.
__global__ __launch_bounds__(256) void gemm2_mfma(const unsigned* __restrict__ X2,   // bf16x2
                                                  const unsigned short* __restrict__ W2t,
                                                  const float* __restrict__ nsrc,
                                                  unsigned short* __restrict__ H2) {
    __shared__ __align__(16) unsigned short Xs[64 * 128];    // 16KB
    __shared__ __align__(16) unsigned short Bs[FOUTP * 128]; // 12KB
    const int t = threadIdx.x;
    const int bm = blockIdx.x * 64;
    const int w = t >> 6;
    const int l = t & 63;
    const int r = l & 15;
    const int kg = l >> 4;

#pragma unroll
    for (int i = 0; i < 4; i++) {
        int idx = t + i * 256;
        int row = idx >> 4;
        int slot = idx & 15;
        int grow = bm + row;
        uint4 packed = make_uint4(0u, 0u, 0u, 0u);
        if (grow < N_NODES) packed = ((const uint4*)X2)[(size_t)grow * 16 + slot];
        *(uint4*)&Xs[row * 128 + ((slot ^ (row & 15)) * 8)] = packed;
    }
#pragma unroll
    for (int i = 0; i < 3; i++) {
        int idx = t + i * 256;
        int row = idx >> 4;
        int slot = idx & 15;
        uint4 packed = *(const uint4*)&W2t[row * 128 + slot * 8];
        *(uint4*)&Bs[row * 128 + ((slot ^ (row & 15)) * 8)] = packed;
    }
    __syncthreads();

    f32x4 acc[3];
#pragma unroll
    for (int c = 0; c < 3; c++) acc[c] = (f32x4){0.f, 0.f, 0.f, 0.f};
    const int arow = w * 16 + r;
#pragma unroll
    for (int ks = 0; ks < 4; ks++) {
        short8 a = *(const short8*)&Xs[arow * 128 + (((ks * 4 + kg) ^ r) * 8)];
#pragma unroll
        for (int c = 0; c < 3; c++) {
            const int brow = c * 16 + r;
            short8 b = *(const short8*)&Bs[brow * 128 + (((ks * 4 + kg) ^ r) * 8)];
            acc[c] = __builtin_amdgcn_mfma_f32_16x16x32_bf16(a, b, acc[c], 0, 0, 0);
        }
    }
#pragma unroll
    for (int j = 0; j < 4; j++) {
        int grow = bm + w * 16 + kg * 4 + j;
        if (grow < N_NODES) {
            float sc = nsrc[grow];
#pragma unroll
            for (int c = 0; c < 3; c++) {
                int col = c * 16 + r;
                if (col < FOUT)
                    H2[(size_t)grow * FOUT + col] = bf1(acc[c][j] * sc);
            }
        }
    }
}

// ---------------- SpMM2 gather (bf16 H2) + finish2: OUT = ndst * sum H2[src] + b2 ----
// 3 nodes per wave: lane = sub*20 + feat (lanes 60-63 idle). feat indexes u32 (2 feats).
__global__ __launch_bounds__(256) void spmm2_gather(const int* __restrict__ rowptr,
                                                    const int* __restrict__ esrc,
                                                    const unsigned* __restrict__ H2,  // bf16x2, 20 u32/row
                                                    const float* __restrict__ ndst,
                                                    const float* __restrict__ b2,
                                                    float* __restrict__ OUT) {
    const int wave = (threadIdx.x >> 6);
    const int lane = threadIdx.x & 63;
    const int sub = lane / 20;            // 0..2 (3 for lanes 60..63)
    const int feat = lane % 20;
    int node = blockIdx.x * 12 + wave * 3 + sub;
    if (sub >= 3 || node >= N_NODES) return;
    int beg = rowptr[node], end = rowptr[node + 1];
    float2 acc0 = make_float2(0.f, 0.f);
    float2 acc1 = make_float2(0.f, 0.f);
    int p = beg;
    for (; p + 1 < end; p += 2) {
        int s0 = esrc[p], s1 = esrc[p + 1];
        unsigned u0 = H2[(size_t)s0 * (FOUT / 2) + feat];
        unsigned u1 = H2[(size_t)s1 * (FOUT / 2) + feat];
        acc0.x += __uint_as_float(u0 << 16);
        acc0.y += __uint_as_float(u0 & 0xffff0000u);
        acc1.x += __uint_as_float(u1 << 16);
        acc1.y += __uint_as_float(u1 & 0xffff0000u);
    }
    if (p < end) {
        int s0 = esrc[p];
        unsigned u0 = H2[(size_t)s0 * (FOUT / 2) + feat];
        acc0.x += __uint_as_float(u0 << 16);
        acc0.y += __uint_as_float(u0 & 0xffff0000u);
    }
    acc0.x += acc1.x; acc0.y += acc1.y;
    float nd = ndst[node];
    float2 b = *(const float2*)(b2 + feat * 2);
    float2 o;
    o.x = fmaf(acc0.x, nd, b.x);
    o.y = fmaf(acc0.y, nd, b.y);
    *(float2*)(OUT + (size_t)node * FOUT + feat * 2) = o;
}

extern "C" void kernel_launch(void* const* d_in, const int* in_sizes, int n_in,
                              void* d_out, int out_size, void* d_ws, size_t ws_size,
                              hipStream_t stream) {
    const float* feat = (const float*)d_in[0];
    const int*   src  = (const int*)d_in[1];
    const int*   dst  = (const int*)d_in[2];
    const float* W1   = (const float*)d_in[3];
    const float* b1   = (const float*)d_in[4];
    const float* W2   = (const float*)d_in[5];
    const float* b2   = (const float*)d_in[6];
    float* out = (float*)d_out;

    char* ws = (char*)d_ws;
    const size_t SZ_BIG = (size_t)N_NODES * FHID * sizeof(float);   // 51.2 MB
    // Layout:
    //  [0, 25.6MB)          Hbf   (bf16 H, gemm1 out)
    //  [SZ_BIG, +12.8MB)    scratch (deg/CSR; dead after scatter2)
    //  [SZ_BIG, +25.6MB)    X2bf  (bf16 X2, spmm1 out; reuses scratch space)
    //  [SZ_BIG+32MB, +8MB)  H2bf  (bf16 H2, gemm2 out)
    unsigned short* Hbf  = (unsigned short*)ws;
    unsigned*       X2u  = (unsigned*)(ws + SZ_BIG);
    unsigned*       scratch = (unsigned*)(ws + SZ_BIG);
    unsigned short* H2bf = (unsigned short*)(ws + SZ_BIG + (32u << 20));
    char* small = ws + 2 * SZ_BIG;
    const size_t SSTRIDE = 401408;                  // 512B-aligned
    float*    nsrc   = (float*)(small);
    float*    ndst   = (float*)(small + SSTRIDE);
    unsigned* degI   = (unsigned*)(small + 2 * SSTRIDE);
    int*      rowptr = (int*)(small + 3 * SSTRIDE);
    unsigned* bsum   = (unsigned*)(small + 4 * SSTRIDE);
    unsigned short* Wt  = (unsigned short*)(small + 5 * SSTRIDE);            // 128KB bf16 W1^T
    unsigned short* W2t = (unsigned short*)(small + 5 * SSTRIDE + 131072);   // 12KB bf16 W2^T padded
    int*      esrc   = (int*)(small + 6 * SSTRIDE);                          // 6.4 MB

    // CSR build (no global atomics, no memset needed)
    deg_hist<<<2 * NRANGE * GH, 256, 0, stream>>>(src, dst, scratch);
    deg_reduce<<<(N_NODES + 255) / 256, 256, 0, stream>>>(scratch, nsrc, ndst, degI);
    scan_blocksum<<<SCAN_NB, 256, 0, stream>>>(degI, bsum);
    scan_bsum<<<1, 128, 0, stream>>>(bsum, rowptr);
    scan_write<<<SCAN_NB, 256, 0, stream>>>(degI, bsum, rowptr);
    mkbase<<<(N_NODES + 255) / 256, 256, 0, stream>>>(scratch, rowptr);
    scatter2<<<NRANGE * GH, 256, 0, stream>>>(src, dst, scratch, esrc);
    wcvt_kernel<<<(FIN * FHID + 255) / 256, 256, 0, stream>>>(W1, Wt);
    w2cvt_kernel<<<(FOUTP * FHID + 255) / 256, 256, 0, stream>>>(W2, W2t);

    gemm1_mfma<<<(N_NODES + 63) / 64, 256, 0, stream>>>(feat, Wt, nsrc, Hbf);
    spmm1_gather<<<(N_NODES + 3) / 4, 256, 0, stream>>>(rowptr, esrc, (const unsigned*)Hbf,
                                                        ndst, b1, X2u);          // X2 (bf16) — scratch now dead
    gemm2_mfma<<<(N_NODES + 63) / 64, 256, 0, stream>>>(X2u, W2t, nsrc, H2bf);
    spmm2_gather<<<(N_NODES + 11) / 12, 256, 0, stream>>>(rowptr, esrc, (const unsigned*)H2bf,
                                                          ndst, b2, out);
}

// Round 7
// 297.390 us; speedup vs baseline: 6.6365x; 1.0665x over previous
//
#include <hip/hip_runtime.h>
#include <hip/hip_bf16.h>

#define N_NODES 100000
#define N_EDGES 1600000
#define FIN 512
#define FHID 128
#define FOUT 40
#define FOUTP 48                // FOUT padded to 3x16 for MFMA

#define SCAN_CHUNK 1024
#define SCAN_NB ((N_NODES + SCAN_CHUNK - 1) / SCAN_CHUNK)   // 98

// CSR-build histogram geometry
#define NRANGE 8
#define RANGE_SZ 12500          // 8 * 12500 = 100000; 50KB LDS u32
#define GH 16                   // edge slices per task
#define EDGE_SLICE (N_EDGES / GH)   // 100000

typedef __attribute__((ext_vector_type(8))) short short8;   // 8 bf16 (4 VGPR)
typedef __attribute__((ext_vector_type(4))) float f32x4;    // MFMA acc

static __device__ inline unsigned short f2bf(float f) {     // cold paths only
    unsigned x = __float_as_uint(f);
    unsigned r = (x + 0x7fffu + ((x >> 16) & 1u)) >> 16;    // RNE
    return (unsigned short)r;
}

// hot-path pair conversion -> v_cvt_pk_bf16_f32 (compiler-emitted)
static __device__ inline unsigned pk2bf(float lo, float hi) {
    __hip_bfloat162 h = __float22bfloat162_rn(make_float2(lo, hi));
    return *(unsigned*)&h;
}
static __device__ inline unsigned short bf1(float f) {
    __hip_bfloat16 h = __float2bfloat16(f);
    return *(unsigned short*)&h;
}

// async global->LDS 16B copy: LDS dest = wave-uniform base + lane*16 (linear);
// swizzling is achieved by pre-swizzling the per-lane GLOBAL source address.
static __device__ inline void gload_lds16(const unsigned short* g, unsigned short* l) {
    __builtin_amdgcn_global_load_lds(
        (const __attribute__((address_space(1))) unsigned int*)(g),
        (__attribute__((address_space(3))) unsigned int*)(l), 16, 0, 0);
}

// ---------------- deg_hist: LDS-privatized degree histograms, no global atomics ----
__global__ __launch_bounds__(256) void deg_hist(const int* __restrict__ src,
                                                const int* __restrict__ dst,
                                                unsigned* __restrict__ scratch) {
    __shared__ unsigned hist[RANGE_SZ];
    const int task = blockIdx.x / GH;
    const int g = blockIdx.x % GH;
    const int a = task / NRANGE;
    const int rg = task % NRANGE;
    const int lo = rg * RANGE_SZ;
    const int t = threadIdx.x;
    for (int i = t; i < RANGE_SZ; i += 256) hist[i] = 0;
    __syncthreads();
    const int* arr = a ? dst : src;
    const int4* p = (const int4*)(arr + g * EDGE_SLICE);
    for (int i = t; i < EDGE_SLICE / 4; i += 256) {
        int4 v = p[i];
        int x;
        x = v.x - lo; if ((unsigned)x < RANGE_SZ) atomicAdd(&hist[x], 1u);
        x = v.y - lo; if ((unsigned)x < RANGE_SZ) atomicAdd(&hist[x], 1u);
        x = v.z - lo; if ((unsigned)x < RANGE_SZ) atomicAdd(&hist[x], 1u);
        x = v.w - lo; if ((unsigned)x < RANGE_SZ) atomicAdd(&hist[x], 1u);
    }
    __syncthreads();
    unsigned* out = scratch + ((size_t)task * GH + g) * RANGE_SZ;
    for (int i = t; i < RANGE_SZ; i += 256) out[i] = hist[i];
}

// ---------------- deg_reduce_scan: degI + norms + per-1024-chunk sums (fused) ----
// block b handles nodes [b*1024, b*1024+1024); writes bsum[b] = sum degI over chunk.
__global__ __launch_bounds__(256) void deg_reduce_scan(const unsigned* __restrict__ scratch,
                                                       float* __restrict__ nsrc,
                                                       float* __restrict__ ndst,
                                                       unsigned* __restrict__ degI,
                                                       unsigned* __restrict__ bsum) {
    __shared__ unsigned red[256];
    const int b = blockIdx.x, t = threadIdx.x;
    unsigned mysum = 0;
#pragma unroll
    for (int i = 0; i < 4; i++) {
        int node = b * SCAN_CHUNK + i * 256 + t;
        if (node < N_NODES) {
            const int rg = node / RANGE_SZ;
            const int off = node % RANGE_SZ;
            const unsigned* ps = scratch + ((size_t)rg * GH) * RANGE_SZ + off;
            const unsigned* pd = scratch + ((size_t)(NRANGE + rg) * GH) * RANGE_SZ + off;
            unsigned so = 0, si = 0;
#pragma unroll
            for (int g = 0; g < GH; g++) {
                so += ps[(size_t)g * RANGE_SZ];
                si += pd[(size_t)g * RANGE_SZ];
            }
            degI[node] = si;
            nsrc[node] = rsqrtf((float)(so < 1u ? 1u : so));
            ndst[node] = rsqrtf((float)(si < 1u ? 1u : si));
            mysum += si;
        }
    }
    red[t] = mysum; __syncthreads();
    for (int off = 128; off > 0; off >>= 1) {
        if (t < off) red[t] += red[t + off];
        __syncthreads();
    }
    if (t == 0) bsum[b] = red[0];
}

__global__ void scan_bsum(unsigned* __restrict__ bsum, int* __restrict__ rowptr) {
    __shared__ unsigned s[128];
    int t = threadIdx.x;
    if (t < SCAN_NB) s[t] = bsum[t];
    __syncthreads();
    if (t == 0) {
        unsigned run = 0;
        for (int i = 0; i < SCAN_NB; i++) { unsigned x = s[i]; s[i] = run; run += x; }
    }
    __syncthreads();
    if (t < SCAN_NB) bsum[t] = s[t];
    if (t == 0) rowptr[N_NODES] = N_EDGES;
}

// ---------------- scan_write + mkbase fused: rowptr AND per-(slice,node) CSR bases ----
__global__ __launch_bounds__(256) void scan_write_mk(const unsigned* __restrict__ deg,
                                                     const unsigned* __restrict__ bsum,
                                                     int* __restrict__ rowptr,
                                                     unsigned* __restrict__ scratch) {
    __shared__ unsigned ts[256];
    int b = blockIdx.x, t = threadIdx.x;
    int base = b * SCAN_CHUNK + t * 4;
    unsigned v[4]; unsigned sum = 0;
#pragma unroll
    for (int i = 0; i < 4; i++) { int idx = base + i; v[i] = (idx < N_NODES) ? deg[idx] : 0u; sum += v[i]; }
    ts[t] = sum; __syncthreads();
    for (int off = 1; off < 256; off <<= 1) {
        unsigned add = (t >= off) ? ts[t - off] : 0u;
        __syncthreads();
        ts[t] += add;
        __syncthreads();
    }
    unsigned excl = (t == 0) ? 0u : ts[t - 1];
    unsigned run = bsum[b] + excl;
#pragma unroll
    for (int i = 0; i < 4; i++) {
        int idx = base + i;
        if (idx < N_NODES) {
            rowptr[idx] = (int)run;
            // mkbase: turn per-slice counts into running CSR bases for this node
            const int rg = idx / RANGE_SZ;
            const int off = idx % RANGE_SZ;
            unsigned* pd = scratch + ((size_t)(NRANGE + rg) * GH) * RANGE_SZ + off;
            unsigned nrun = run;
#pragma unroll
            for (int g = 0; g < GH; g++) {
                unsigned c = pd[(size_t)g * RANGE_SZ];
                pd[(size_t)g * RANGE_SZ] = nrun;
                nrun += c;
            }
        }
        run += v[i];
    }
}

// ---------------- scatter2: CSR slot assignment via LDS cursors only ----------------
__global__ __launch_bounds__(256) void scatter2(const int* __restrict__ src,
                                                const int* __restrict__ dst,
                                                const unsigned* __restrict__ scratch,
                                                int* __restrict__ esrc) {
    __shared__ unsigned cur[RANGE_SZ];
    const int rg = blockIdx.x / GH;
    const int g = blockIdx.x % GH;
    const int lo = rg * RANGE_SZ;
    const int t = threadIdx.x;
    const unsigned* base = scratch + ((size_t)(NRANGE + rg) * GH + g) * RANGE_SZ;
    for (int i = t; i < RANGE_SZ; i += 256) cur[i] = base[i];
    __syncthreads();
    const int4* pd = (const int4*)(dst + g * EDGE_SLICE);
    const int4* ps = (const int4*)(src + g * EDGE_SLICE);
    for (int i = t; i < EDGE_SLICE / 4; i += 256) {
        int4 d4 = pd[i];
        int4 s4 = ps[i];
        int x;
        x = d4.x - lo; if ((unsigned)x < RANGE_SZ) esrc[atomicAdd(&cur[x], 1u)] = s4.x;
        x = d4.y - lo; if ((unsigned)x < RANGE_SZ) esrc[atomicAdd(&cur[x], 1u)] = s4.y;
        x = d4.z - lo; if ((unsigned)x < RANGE_SZ) esrc[atomicAdd(&cur[x], 1u)] = s4.z;
        x = d4.w - lo; if ((unsigned)x < RANGE_SZ) esrc[atomicAdd(&cur[x], 1u)] = s4.w;
    }
}

// ---------------- weights -> bf16 transposed (both layers, one kernel) ----------------
__global__ __launch_bounds__(256) void wcvt_all(const float* __restrict__ W1,
                                                const float* __restrict__ W2,
                                                unsigned short* __restrict__ Wt,
                                                unsigned short* __restrict__ W2t) {
    int j = blockIdx.x * blockDim.x + threadIdx.x;
    if (j < FIN * FHID) {                 // Wt[n][k] = bf16(W1[k][n]); j = k*128+n
        int k = j >> 7;
        int n = j & 127;
        Wt[n * FIN + k] = f2bf(W1[j]);
    } else if (j < FIN * FHID + FOUTP * FHID) {
        int jj = j - FIN * FHID;          // W2t[n][k]; jj = n*128+k
        int n = jj >> 7;
        int k = jj & 127;
        W2t[jj] = (n < FOUT) ? f2bf(W2[k * FOUT + n]) : (unsigned short)0;
    }
}

// ---------------- GEMM1 (bf16 MFMA): H = nsrc * (bf16(X) @ bf16(W1)), H stored bf16 ----
// B-tile staged via global_load_lds (pure copy, swizzle folded into global src addr);
// X-tile staged manually (fp32->bf16 conversion required).
__global__ __launch_bounds__(256) void gemm1_mfma(const float* __restrict__ X,
                                                  const unsigned short* __restrict__ Wt,
                                                  const float* __restrict__ nsrc,
                                                  unsigned short* __restrict__ H) {
    __shared__ __align__(16) unsigned short Xs[64 * 64];    // 8KB  [row][k]
    __shared__ __align__(16) unsigned short Bs[128 * 64];   // 16KB [col][k]
    const int t = threadIdx.x;
    const int bm = blockIdx.x * 64;
    const int w = t >> 6;
    const int l = t & 63;
    const int r = l & 15;
    const int kg = l >> 4;

    f32x4 acc[8];
#pragma unroll
    for (int c = 0; c < 8; c++) acc[c] = (f32x4){0.f, 0.f, 0.f, 0.f};

    for (int s = 0; s < FIN / 64; ++s) {
        const int k0 = s * 64;
        // ---- B staging: 16 chunks of 1KB; chunk c -> cols c*8..c*8+7
        //      lane l covers col = c*8 + l/8, swizzled slot' = l&7
        //      global src pre-unswizzled: slot = slot' ^ (col&7)
#pragma unroll
        for (int i = 0; i < 4; i++) {
            int c = i * 4 + w;
            int col = c * 8 + (l >> 3);
            int slotp = l & 7;
            gload_lds16(Wt + (size_t)col * FIN + k0 + ((slotp ^ (col & 7)) * 8),
                        Bs + c * 512);
        }
        // ---- X staging (manual, with conversion)
#pragma unroll
        for (int i = 0; i < 2; i++) {
            int idx = t + i * 256;
            int row = idx >> 3;
            int slot = idx & 7;
            int grow = bm + row;
            uint4 packed = make_uint4(0u, 0u, 0u, 0u);
            if (grow < N_NODES) {
                const float4* p = (const float4*)(X + (size_t)grow * FIN + k0 + slot * 8);
                float4 v0 = p[0];
                float4 v1 = p[1];
                packed.x = pk2bf(v0.x, v0.y);
                packed.y = pk2bf(v0.z, v0.w);
                packed.z = pk2bf(v1.x, v1.y);
                packed.w = pk2bf(v1.z, v1.w);
            }
            *(uint4*)&Xs[row * 64 + ((slot ^ (row & 7)) * 8)] = packed;
        }
        __syncthreads();
        const int arow = w * 16 + r;
        short8 a0 = *(const short8*)&Xs[arow * 64 + (((0 + kg) ^ (r & 7)) * 8)];
        short8 a1 = *(const short8*)&Xs[arow * 64 + (((4 + kg) ^ (r & 7)) * 8)];
#pragma unroll
        for (int c = 0; c < 8; c++) {
            const int brow = c * 16 + r;
            short8 b0 = *(const short8*)&Bs[brow * 64 + (((0 + kg) ^ (r & 7)) * 8)];
            short8 b1 = *(const short8*)&Bs[brow * 64 + (((4 + kg) ^ (r & 7)) * 8)];
            acc[c] = __builtin_amdgcn_mfma_f32_16x16x32_bf16(a0, b0, acc[c], 0, 0, 0);
            acc[c] = __builtin_amdgcn_mfma_f32_16x16x32_bf16(a1, b1, acc[c], 0, 0, 0);
        }
        __syncthreads();
    }
    // epilogue: scale by nsrc[row], store bf16. C/D: col=lane&15, row=(lane>>4)*4+reg
#pragma unroll
    for (int j = 0; j < 4; j++) {
        int grow = bm + w * 16 + kg * 4 + j;
        if (grow < N_NODES) {
            float sc = nsrc[grow];
#pragma unroll
            for (int c = 0; c < 8; c++)
                H[(size_t)grow * FHID + c * 16 + r] = bf1(acc[c][j] * sc);
        }
    }
}

// ---------------- SpMM1 gather (bf16 H) + finish1: X2 = relu(ndst*sum H[src] + b1), bf16 out ----
// unroll-8, 4 independent accumulators: 8 H-rows + 8 esrc in flight per wave (latency-bound).
__global__ __launch_bounds__(256) void spmm1_gather(const int* __restrict__ rowptr,
                                                    const int* __restrict__ esrc,
                                                    const unsigned* __restrict__ H,   // bf16x2
                                                    const float* __restrict__ ndst,
                                                    const float* __restrict__ b1,
                                                    unsigned* __restrict__ X2) {      // bf16x2
    int node = blockIdx.x * (blockDim.x >> 6) + (threadIdx.x >> 6);
    if (node >= N_NODES) return;
    int lane = threadIdx.x & 63;
    int beg = rowptr[node], end = rowptr[node + 1];
    float2 a0 = make_float2(0.f, 0.f), a1 = make_float2(0.f, 0.f);
    float2 a2 = make_float2(0.f, 0.f), a3 = make_float2(0.f, 0.f);
    int p = beg;
    for (; p + 7 < end; p += 8) {
        int s0 = esrc[p],     s1 = esrc[p + 1], s2 = esrc[p + 2], s3 = esrc[p + 3];
        int s4 = esrc[p + 4], s5 = esrc[p + 5], s6 = esrc[p + 6], s7 = esrc[p + 7];
        unsigned u0 = H[(size_t)s0 * (FHID / 2) + lane];
        unsigned u1 = H[(size_t)s1 * (FHID / 2) + lane];
        unsigned u2 = H[(size_t)s2 * (FHID / 2) + lane];
        unsigned u3 = H[(size_t)s3 * (FHID / 2) + lane];
        unsigned u4 = H[(size_t)s4 * (FHID / 2) + lane];
        unsigned u5 = H[(size_t)s5 * (FHID / 2) + lane];
        unsigned u6 = H[(size_t)s6 * (FHID / 2) + lane];
        unsigned u7 = H[(size_t)s7 * (FHID / 2) + lane];
        a0.x += __uint_as_float(u0 << 16) + __uint_as_float(u1 << 16);
        a0.y += __uint_as_float(u0 & 0xffff0000u) + __uint_as_float(u1 & 0xffff0000u);
        a1.x += __uint_as_float(u2 << 16) + __uint_as_float(u3 << 16);
        a1.y += __uint_as_float(u2 & 0xffff0000u) + __uint_as_float(u3 & 0xffff0000u);
        a2.x += __uint_as_float(u4 << 16) + __uint_as_float(u5 << 16);
        a2.y += __uint_as_float(u4 & 0xffff0000u) + __uint_as_float(u5 & 0xffff0000u);
        a3.x += __uint_as_float(u6 << 16) + __uint_as_float(u7 << 16);
        a3.y += __uint_as_float(u6 & 0xffff0000u) + __uint_as_float(u7 & 0xffff0000u);
    }
    for (; p + 1 < end; p += 2) {
        int s0 = esrc[p], s1 = esrc[p + 1];
        unsigned u0 = H[(size_t)s0 * (FHID / 2) + lane];
        unsigned u1 = H[(size_t)s1 * (FHID / 2) + lane];
        a0.x += __uint_as_float(u0 << 16) + __uint_as_float(u1 << 16);
        a0.y += __uint_as_float(u0 & 0xffff0000u) + __uint_as_float(u1 & 0xffff0000u);
    }
    if (p < end) {
        int s0 = esrc[p];
        unsigned u0 = H[(size_t)s0 * (FHID / 2) + lane];
        a1.x += __uint_as_float(u0 << 16);
        a1.y += __uint_as_float(u0 & 0xffff0000u);
    }
    float ax = (a0.x + a1.x) + (a2.x + a3.x);
    float ay = (a0.y + a1.y) + (a2.y + a3.y);
    float nd = ndst[node];
    float2 b = *(const float2*)(b1 + lane * 2);
    float ox = fmaxf(fmaf(ax, nd, b.x), 0.f);
    float oy = fmaxf(fmaf(ay, nd, b.y), 0.f);
    X2[(size_t)node * (FHID / 2) + lane] = pk2bf(ox, oy);
}

// ---------------- GEMM2 (bf16 MFMA, single-shot K=128): H2 = nsrc * (X2 @ W2), bf16 out ----
// Both stagings are pure copies -> global_load_lds with pre-swizzled global src.
__global__ __launch_bounds__(256) void gemm2_mfma(const unsigned short* __restrict__ X2,  // bf16
                                                  const unsigned short* __restrict__ W2t,
                                                  const float* __restrict__ nsrc,
                                                  unsigned short* __restrict__ H2) {
    __shared__ __align__(16) unsigned short Xs[64 * 128];    // 16KB
    __shared__ __align__(16) unsigned short Bs[FOUTP * 128]; // 12KB
    const int t = threadIdx.x;
    const int bm = blockIdx.x * 64;
    const int w = t >> 6;
    const int l = t & 63;
    const int r = l & 15;
    const int kg = l >> 4;

    // X2 staging: 16 chunks of 1KB; chunk c -> rows c*4..c*4+3 of the tile.
    // lane l: row = c*4 + l/16, slot' = l&15; global src slot = slot' ^ (row&15).
    // OOB rows (grow >= N_NODES) read garbage from within d_ws — affects only
    // output rows >= N_NODES, which are never stored (MFMA rows are independent).
#pragma unroll
    for (int i = 0; i < 4; i++) {
        int c = i * 4 + w;
        int row = c * 4 + (l >> 4);
        int slotp = l & 15;
        size_t grow = (size_t)(bm + row);
        if (grow >= N_NODES) grow = N_NODES - 1;   // clamp: stay in valid memory
        gload_lds16(X2 + grow * FHID + ((slotp ^ (row & 15)) * 8), Xs + c * 512);
    }
    // W2t staging: 12 chunks of 1KB; chunk c -> rows c*4..c*4+3 (48 rows total)
#pragma unroll
    for (int i = 0; i < 3; i++) {
        int c = i * 4 + w;
        int row = c * 4 + (l >> 4);
        int slotp = l & 15;
        gload_lds16(W2t + row * FHID + ((slotp ^ (row & 15)) * 8), Bs + c * 512);
    }
    __syncthreads();

    f32x4 acc[3];
#pragma unroll
    for (int c = 0; c < 3; c++) acc[c] = (f32x4){0.f, 0.f, 0.f, 0.f};
    const int arow = w * 16 + r;
#pragma unroll
    for (int ks = 0; ks < 4; ks++) {
        short8 a = *(const short8*)&Xs[arow * 128 + (((ks * 4 + kg) ^ r) * 8)];
#pragma unroll
        for (int c = 0; c < 3; c++) {
            const int brow = c * 16 + r;
            short8 b = *(const short8*)&Bs[brow * 128 + (((ks * 4 + kg) ^ r) * 8)];
            acc[c] = __builtin_amdgcn_mfma_f32_16x16x32_bf16(a, b, acc[c], 0, 0, 0);
        }
    }
#pragma unroll
    for (int j = 0; j < 4; j++) {
        int grow = bm + w * 16 + kg * 4 + j;
        if (grow < N_NODES) {
            float sc = nsrc[grow];
#pragma unroll
            for (int c = 0; c < 3; c++) {
                int col = c * 16 + r;
                if (col < FOUT)
                    H2[(size_t)grow * FOUT + col] = bf1(acc[c][j] * sc);
            }
        }
    }
}

// ---------------- SpMM2 gather (bf16 H2) + finish2: OUT = ndst * sum H2[src] + b2 ----
// 3 nodes per wave: lane = sub*20 + feat (lanes 60-63 idle). feat indexes u32 (2 feats).
__global__ __launch_bounds__(256) void spmm2_gather(const int* __restrict__ rowptr,
                                                    const int* __restrict__ esrc,
                                                    const unsigned* __restrict__ H2,  // bf16x2, 20 u32/row
                                                    const float* __restrict__ ndst,
                                                    const float* __restrict__ b2,
                                                    float* __restrict__ OUT) {
    const int wave = (threadIdx.x >> 6);
    const int lane = threadIdx.x & 63;
    const int sub = lane / 20;            // 0..2 (3 for lanes 60..63)
    const int feat = lane % 20;
    int node = blockIdx.x * 12 + wave * 3 + sub;
    if (sub >= 3 || node >= N_NODES) return;
    int beg = rowptr[node], end = rowptr[node + 1];
    float2 a0 = make_float2(0.f, 0.f), a1 = make_float2(0.f, 0.f);
    float2 a2 = make_float2(0.f, 0.f), a3 = make_float2(0.f, 0.f);
    int p = beg;
    for (; p + 3 < end; p += 4) {
        int s0 = esrc[p], s1 = esrc[p + 1], s2 = esrc[p + 2], s3 = esrc[p + 3];
        unsigned u0 = H2[(size_t)s0 * (FOUT / 2) + feat];
        unsigned u1 = H2[(size_t)s1 * (FOUT / 2) + feat];
        unsigned u2 = H2[(size_t)s2 * (FOUT / 2) + feat];
        unsigned u3 = H2[(size_t)s3 * (FOUT / 2) + feat];
        a0.x += __uint_as_float(u0 << 16);
        a0.y += __uint_as_float(u0 & 0xffff0000u);
        a1.x += __uint_as_float(u1 << 16);
        a1.y += __uint_as_float(u1 & 0xffff0000u);
        a2.x += __uint_as_float(u2 << 16);
        a2.y += __uint_as_float(u2 & 0xffff0000u);
        a3.x += __uint_as_float(u3 << 16);
        a3.y += __uint_as_float(u3 & 0xffff0000u);
    }
    for (; p < end; ++p) {
        int s0 = esrc[p];
        unsigned u0 = H2[(size_t)s0 * (FOUT / 2) + feat];
        a0.x += __uint_as_float(u0 << 16);
        a0.y += __uint_as_float(u0 & 0xffff0000u);
    }
    float ax = (a0.x + a1.x) + (a2.x + a3.x);
    float ay = (a0.y + a1.y) + (a2.y + a3.y);
    float nd = ndst[node];
    float2 b = *(const float2*)(b2 + feat * 2);
    float2 o;
    o.x = fmaf(ax, nd, b.x);
    o.y = fmaf(ay, nd, b.y);
    *(float2*)(OUT + (size_t)node * FOUT + feat * 2) = o;
}

extern "C" void kernel_launch(void* const* d_in, const int* in_sizes, int n_in,
                              void* d_out, int out_size, void* d_ws, size_t ws_size,
                              hipStream_t stream) {
    const float* feat = (const float*)d_in[0];
    const int*   src  = (const int*)d_in[1];
    const int*   dst  = (const int*)d_in[2];
    const float* W1   = (const float*)d_in[3];
    const float* b1   = (const float*)d_in[4];
    const float* W2   = (const float*)d_in[5];
    const float* b2   = (const float*)d_in[6];
    float* out = (float*)d_out;

    char* ws = (char*)d_ws;
    const size_t SZ_BIG = (size_t)N_NODES * FHID * sizeof(float);   // 51.2 MB
    // Layout:
    //  [0, 25.6MB)          Hbf   (bf16 H, gemm1 out)
    //  [SZ_BIG, +12.8MB)    scratch (deg/CSR; dead after scatter2)
    //  [SZ_BIG, +25.6MB)    X2bf  (bf16 X2, spmm1 out; reuses scratch space)
    //  [SZ_BIG+32MB, +8MB)  H2bf  (bf16 H2, gemm2 out)
    unsigned short* Hbf  = (unsigned short*)ws;
    unsigned short* X2bf = (unsigned short*)(ws + SZ_BIG);
    unsigned*       scratch = (unsigned*)(ws + SZ_BIG);
    unsigned short* H2bf = (unsigned short*)(ws + SZ_BIG + (32u << 20));
    char* small = ws + 2 * SZ_BIG;
    const size_t SSTRIDE = 401408;                  // 512B-aligned
    float*    nsrc   = (float*)(small);
    float*    ndst   = (float*)(small + SSTRIDE);
    unsigned* degI   = (unsigned*)(small + 2 * SSTRIDE);
    int*      rowptr = (int*)(small + 3 * SSTRIDE);
    unsigned* bsum   = (unsigned*)(small + 4 * SSTRIDE);
    unsigned short* Wt  = (unsigned short*)(small + 5 * SSTRIDE);            // 128KB bf16 W1^T
    unsigned short* W2t = (unsigned short*)(small + 5 * SSTRIDE + 131072);   // 12KB bf16 W2^T padded
    int*      esrc   = (int*)(small + 6 * SSTRIDE);                          // 6.4 MB

    // CSR build (no global atomics, no memset needed)
    deg_hist<<<2 * NRANGE * GH, 256, 0, stream>>>(src, dst, scratch);
    deg_reduce_scan<<<SCAN_NB, 256, 0, stream>>>(scratch, nsrc, ndst, degI, bsum);
    scan_bsum<<<1, 128, 0, stream>>>(bsum, rowptr);
    scan_write_mk<<<SCAN_NB, 256, 0, stream>>>(degI, bsum, rowptr, scratch);
    scatter2<<<NRANGE * GH, 256, 0, stream>>>(src, dst, scratch, esrc);
    wcvt_all<<<(FIN * FHID + FOUTP * FHID + 255) / 256, 256, 0, stream>>>(W1, W2, Wt, W2t);

    gemm1_mfma<<<(N_NODES + 63) / 64, 256, 0, stream>>>(feat, Wt, nsrc, Hbf);
    spmm1_gather<<<(N_NODES + 3) / 4, 256, 0, stream>>>(rowptr, esrc, (const unsigned*)Hbf,
                                                        ndst, b1, (unsigned*)X2bf);   // scratch now dead
    gemm2_mfma<<<(N_NODES + 63) / 64, 256, 0, stream>>>(X2bf, W2t, nsrc, H2bf);
    spmm2_gather<<<(N_NODES + 11) / 12, 256, 0, stream>>>(rowptr, esrc, (const unsigned*)H2bf,
                                                          ndst, b2, out);
}